// Round 16
// baseline (2398.930 us; speedup 1.0000x reference)
//
#include <hip/hip_runtime.h>
#include <math.h>

// AVWDCRNN round 16 (all-f32). r15=992us. Changes:
//  - k_wpool4 reuse-blocked: pool chunk staged in LDS, reused across 16 nodes
//    (L2 reads 1.2GB -> ~95MB); 57 -> ~28us.
//  - k_py 32-row tiles (768/512 blocks, 26KB LDS) - r12-proven shape.
//  - k_pm 32-o slices (2048/1024 blocks, half W stream per block).
// FP reduction order unchanged from r15 (absmax should stay 0.0078125).

#define NF __restrict__
constexpr int N_ = 256, B_ = 8, T_ = 12, H_ = 64, E_ = 16;

__global__ void k_sentinel(float* NF out) { out[0] = 1.0e6f; }

// ---------------- adj = softmax(relu(ne ne^T), axis=1) ----------------
__global__ void k_adj(const float* NF ne, float* NF adj) {
    int n = blockIdx.x, m = threadIdx.x;
    __shared__ float en[E_];
    __shared__ float red[256];
    if (m < E_) en[m] = ne[n * E_ + m];
    __syncthreads();
    float s = 0.f;
#pragma unroll
    for (int d = 0; d < E_; d++) s += en[d] * ne[m * E_ + d];
    s = fmaxf(s, 0.f);
    red[m] = s; __syncthreads();
    for (int st = 128; st > 0; st >>= 1) { if (m < st) red[m] = fmaxf(red[m], red[m + st]); __syncthreads(); }
    float mx = red[0]; __syncthreads();
    float e = __expf(s - mx);
    red[m] = e; __syncthreads();
    for (int st = 128; st > 0; st >>= 1) { if (m < st) red[m] += red[m + st]; __syncthreads(); }
    adj[(size_t)n * N_ + m] = e / red[0];
}

// ------------- all four biases in one launch -------------
__global__ void k_bias4(const float* NF ne, const float* NF gb0, const float* NF ub0,
                        const float* NF gb1, const float* NF ub1,
                        float* NF Bg0, float* NF Bu0, float* NF Bg1, float* NF Bu1) {
    int n = blockIdx.x, tid = threadIdx.x;
    __shared__ float e[E_];
    if (tid < E_) e[tid] = ne[n * E_ + tid];
    __syncthreads();
    if (tid < 128) {
        float a0 = 0.f, a1 = 0.f;
#pragma unroll
        for (int d = 0; d < E_; d++) { a0 = fmaf(e[d], gb0[d * 128 + tid], a0); a1 = fmaf(e[d], gb1[d * 128 + tid], a1); }
        Bg0[(size_t)n * 128 + tid] = a0; Bg1[(size_t)n * 128 + tid] = a1;
    } else {
        int o = tid - 128;
        float a0 = 0.f, a1 = 0.f;
#pragma unroll
        for (int d = 0; d < E_; d++) { a0 = fmaf(e[d], ub0[d * 64 + o], a0); a1 = fmaf(e[d], ub1[d * 64 + o], a1); }
        Bu0[(size_t)n * 64 + o] = a0; Bu1[(size_t)n * 64 + o] = a1;
    }
}

// ------------- single-buffer W pool (fallback tier) -------------
__global__ void k_wpool(const float* NF ne, const float* NF wp, float* NF W,
                        int I2, int O4, int total4) {
    int idx4 = blockIdx.x * 256 + threadIdx.x;
    if (idx4 >= total4) return;
    int o4 = idx4 % O4; int rem = idx4 / O4; int j = rem % I2; int n = rem / I2;
    const float* nrow = ne + n * E_;
    float ax = 0.f, ay = 0.f, az = 0.f, aw = 0.f;
#pragma unroll
    for (int d = 0; d < E_; d++) {
        float e = nrow[d];
        const float4 w = *(const float4*)&wp[(((size_t)d * I2 + j) * O4 + o4) * 4];
        ax = fmaf(e, w.x, ax); ay = fmaf(e, w.y, ay); az = fmaf(e, w.z, az); aw = fmaf(e, w.w, aw);
    }
    float4 r; r.x = ax; r.y = ay; r.z = az; r.w = aw;
    *(float4*)&W[(size_t)idx4 * 4] = r;
}

// ------------- all 4 W pools: reuse-blocked (64 col4 x 16 nodes/block) -------------
// grid 291 col-chunks x 16 node-blocks = 4656.
__global__ __launch_bounds__(256) void k_wpool4(const float* NF ne,
                         const float* NF gw0, const float* NF uw0,
                         const float* NF gw1, const float* NF uw1,
                         float* NF Wg0, float* NF Wu0, float* NF Wg1, float* NF Wu1) {
    int cb = blockIdx.x % 291, nb = blockIdx.x / 291;
    const float* wp; float* W; int O4, c0;
    if (cb < 66)       { wp = gw0; W = Wg0; O4 = 4224; c0 = cb * 64; }
    else if (cb < 99)  { wp = uw0; W = Wu0; O4 = 2112; c0 = (cb - 66) * 64; }
    else if (cb < 227) { wp = gw1; W = Wg1; O4 = 8192; c0 = (cb - 99) * 64; }
    else               { wp = uw1; W = Wu1; O4 = 4096; c0 = (cb - 227) * 64; }
    __shared__ float4 PL[16][64];    // pool chunk: 16 d x 64 col4 (16 KB)
    __shared__ float  eL[16][17];
    int tid = threadIdx.x;
#pragma unroll
    for (int q = 0; q < 4; q++) {
        int idx = q * 256 + tid; int d = idx >> 6, c = idx & 63;
        PL[d][c] = *(const float4*)&wp[((size_t)d * O4 + c0 + c) * 4];
    }
    int n0 = nb * 16;
    { int nn = tid >> 4, d = tid & 15; eL[nn][d] = ne[(n0 + nn) * E_ + d]; }
    __syncthreads();
    int c = tid & 63, ng = tid >> 6;
#pragma unroll
    for (int q = 0; q < 4; q++) {
        int nn = ng * 4 + q;
        float ax = 0.f, ay = 0.f, az = 0.f, aw = 0.f;
#pragma unroll
        for (int d = 0; d < E_; d++) {
            float e = eL[nn][d];
            float4 w = PL[d][c];
            ax = fmaf(e, w.x, ax); ay = fmaf(e, w.y, ay);
            az = fmaf(e, w.z, az); aw = fmaf(e, w.w, aw);
        }
        float4 r; r.x = ax; r.y = ay; r.z = az; r.w = aw;
        *(float4*)&W[((size_t)(n0 + nn) * O4 + c0 + c) * 4] = r;
    }
}

// ------------- E[tb,i,j] = exp(-L1(pa_i, pa_j)) ; tiled 64x64 -------------
__global__ __launch_bounds__(256) void k_sub_t(const float* NF pa, float* NF Ebuf) {
    int bx = blockIdx.x, tb = blockIdx.y;    // grid (16, 96)
    int it = bx & 3, jt = bx >> 2;
    int t = tb / B_, b = tb % B_;
    const float* p = pa + ((size_t)b * T_ + t) * N_ * H_;
    __shared__ float piT[64][64];
    __shared__ float pjT[64][64];
    int tid = threadIdx.x;
    int i0 = it * 64, j0 = jt * 64;
#pragma unroll
    for (int q = 0; q < 4; q++) {
        int idx = q * 256 + tid; int hq = idx & 15, i = idx >> 4;
        float4 v = *(const float4*)&p[(size_t)(i0 + i) * 64 + hq * 4];
        piT[hq * 4 + 0][i] = v.x; piT[hq * 4 + 1][i] = v.y; piT[hq * 4 + 2][i] = v.z; piT[hq * 4 + 3][i] = v.w;
        float4 w = *(const float4*)&p[(size_t)(j0 + i) * 64 + hq * 4];
        pjT[hq * 4 + 0][i] = w.x; pjT[hq * 4 + 1][i] = w.y; pjT[hq * 4 + 2][i] = w.z; pjT[hq * 4 + 3][i] = w.w;
    }
    __syncthreads();
    int jg = tid & 15, ig = tid >> 4;
    float acc[4][4];
#pragma unroll
    for (int a = 0; a < 4; a++)
#pragma unroll
        for (int c = 0; c < 4; c++) acc[a][c] = 0.f;
    for (int h = 0; h < 64; h++) {
        float4 a4 = *(const float4*)&piT[h][ig * 4];
        float4 b4 = *(const float4*)&pjT[h][jg * 4];
        float av[4] = { a4.x, a4.y, a4.z, a4.w };
        float bv[4] = { b4.x, b4.y, b4.z, b4.w };
#pragma unroll
        for (int a = 0; a < 4; a++)
#pragma unroll
            for (int c = 0; c < 4; c++) acc[a][c] += fabsf(av[a] - bv[c]);
    }
    float* dst = Ebuf + (size_t)tb * N_ * N_;
#pragma unroll
    for (int a = 0; a < 4; a++) {
        float4 o; o.x = __expf(-acc[a][0]); o.y = __expf(-acc[a][1]);
        o.z = __expf(-acc[a][2]); o.w = __expf(-acc[a][3]);
        *(float4*)&dst[(size_t)(i0 + ig * 4 + a) * N_ + j0 + jg * 4] = o;
    }
}

// ------------- column softmax normalize in-place -------------
__global__ void k_norm(float* NF Ebuf) {
    int tb = blockIdx.x, tid = threadIdx.x;   // 96 x 1024
    int j = tid & 255, q = tid >> 8;
    float* s = Ebuf + (size_t)tb * 65536;
    __shared__ float red[4][256];
    float S = 0.f;
    for (int i = q * 64; i < q * 64 + 64; ++i) S += s[(size_t)i * N_ + j];
    red[q][j] = S; __syncthreads();
    float inv = 1.f / (red[0][j] + red[1][j] + red[2][j] + red[3][j]);
    for (int i = q * 64; i < q * 64 + 64; ++i) s[(size_t)i * N_ + j] *= inv;
}

// ------------- A2[tb] = adj @ E'[tb]  (64x64 out-tiles, 32-m chunks) -------------
__global__ __launch_bounds__(256) void k_a2(const float* NF adjm, const float* NF Ebuf, float* NF A2) {
    int rt = blockIdx.x & 3, ct = blockIdx.x >> 2;   // grid (16, 96)
    int tb = blockIdx.y;
    const float* U = Ebuf + (size_t)tb * N_ * N_;
    int r0 = rt * 64, c0 = ct * 64;
    __shared__ float SL[64][33];
    __shared__ float UL[32][72];
    int tid = threadIdx.x, cg = tid & 15, rg = tid >> 4;
    float acc[4][4];
#pragma unroll
    for (int a = 0; a < 4; a++)
#pragma unroll
        for (int c = 0; c < 4; c++) acc[a][c] = 0.f;
    for (int mc = 0; mc < 8; ++mc) {
        int m0 = mc * 32;
#pragma unroll
        for (int q = 0; q < 2; q++) {
            int idx = q * 256 + tid;
            int r = idx >> 3, mq = idx & 7;
            float4 v = *(const float4*)&adjm[(size_t)(r0 + r) * N_ + m0 + mq * 4];
            SL[r][mq * 4 + 0] = v.x; SL[r][mq * 4 + 1] = v.y;
            SL[r][mq * 4 + 2] = v.z; SL[r][mq * 4 + 3] = v.w;
            int mm = idx >> 4, c4 = idx & 15;
            float4 u = *(const float4*)&U[(size_t)(m0 + mm) * N_ + c0 + c4 * 4];
            *(float4*)&UL[mm][c4 * 4] = u;
        }
        __syncthreads();
        for (int mm = 0; mm < 32; ++mm) {
            float4 uv = *(const float4*)&UL[mm][cg * 4];
            float sv[4];
#pragma unroll
            for (int a = 0; a < 4; a++) sv[a] = SL[rg * 4 + a][mm];
#pragma unroll
            for (int a = 0; a < 4; a++) {
                acc[a][0] = fmaf(sv[a], uv.x, acc[a][0]);
                acc[a][1] = fmaf(sv[a], uv.y, acc[a][1]);
                acc[a][2] = fmaf(sv[a], uv.z, acc[a][2]);
                acc[a][3] = fmaf(sv[a], uv.w, acc[a][3]);
            }
        }
        __syncthreads();
    }
    float* dst = A2 + (size_t)tb * N_ * N_;
#pragma unroll
    for (int a = 0; a < 4; a++) {
        float4 o; o.x = acc[a][0]; o.y = acc[a][1]; o.z = acc[a][2]; o.w = acc[a][3];
        *(float4*)&dst[(size_t)(r0 + rg * 4 + a) * N_ + c0 + cg * 4] = o;
    }
}

// ------------- Y0X = S'_k @ x  (64-row tiles, 4-way m-split + shfl) -------------
__global__ __launch_bounds__(256) void k_y0x(const float* NF Ebuf, const float* NF A2,
                                             const float* NF x, float* NF y0x) {
    int rt = blockIdx.x, tbk = blockIdx.y;   // grid (4, 192)
    int tb = tbk >> 1, kk = tbk & 1;
    int t = tb / B_, b = tb % B_;
    const float* S = (kk ? A2 : Ebuf) + (size_t)tb * N_ * N_;
    const float* xb = x + ((size_t)b * T_ + t) * N_ * 2;
    __shared__ float SL[64][65];
    __shared__ float xw[64][2];
    int tid = threadIdx.x, rg = tid >> 2, mg = tid & 3;
    int r0 = rt * 64;
    float a0 = 0.f, a1 = 0.f;
    for (int mc = 0; mc < 4; ++mc) {
        int m0 = mc * 64;
#pragma unroll
        for (int q = 0; q < 4; q++) {
            int idx = q * 256 + tid; int r = idx >> 4, mq = idx & 15;
            float4 v = *(const float4*)&S[(size_t)(r0 + r) * N_ + m0 + mq * 4];
            SL[r][mq * 4 + 0] = v.x; SL[r][mq * 4 + 1] = v.y;
            SL[r][mq * 4 + 2] = v.z; SL[r][mq * 4 + 3] = v.w;
        }
        if (tid < 128) xw[tid >> 1][tid & 1] = xb[(size_t)(m0 + (tid >> 1)) * 2 + (tid & 1)];
        __syncthreads();
        for (int mm = mg * 16; mm < mg * 16 + 16; ++mm) {
            float s = SL[rg][mm];
            a0 = fmaf(s, xw[mm][0], a0); a1 = fmaf(s, xw[mm][1], a1);
        }
        __syncthreads();
    }
    a0 += __shfl_xor(a0, 1); a0 += __shfl_xor(a0, 2);
    a1 += __shfl_xor(a1, 1); a1 += __shfl_xor(a1, 2);
    if (mg == 0) {
        y0x[(((size_t)tb * 2 + kk) * N_ + r0 + rg) * 2 + 0] = a0;
        y0x[(((size_t)tb * 2 + kk) * N_ + r0 + rg) * 2 + 1] = a1;
    }
}

// ------------- sa init for both layers -------------
__global__ void k_init2(const float* NF ist, const float* NF pa,
                        float* NF u1sa0, float* NF u1sa1) {
    int idx = blockIdx.x * 256 + threadIdx.x;   // 262144
    int l = idx >> 17, r = idx & 131071;
    int b = r >> 14, rem = r & 16383;
    float v = ist[(size_t)l * 131072 + r] + pa[(size_t)b * T_ * 16384 + rem];
    if (l == 0) u1sa0[r] = v; else u1sa1[r] = v;
}

// ========== merged y phase, 2-way m-split, 32-row tiles ==========
// l0: bid<2*nb0: ms=bid&1, rest=bid>>1: rt=rest&7, g=rest>>3.
// l1: idx=bid-2*nb0: ms=idx&1, rest=idx>>1: rt=rest&7, g=(rest>>3)&15, cs=(rest>>7)+cs_off.
__global__ __launch_bounds__(256) void k_py(
    const float* NF Et0, const float* NF A2t0, const float* NF u0,
    const float* NF Et1, const float* NF A2t1, const float* NF cr, long crb,
    const float* NF u1s, float* NF yb0, float* NF yb1, int nb0, int cs_off)
{
    int bid = blockIdx.x, tid = threadIdx.x;
    int layer, rt, g, cs, ms;
    if (bid < 2 * nb0) { layer = 0; ms = bid & 1; int rest = bid >> 1; rt = rest & 7; g = rest >> 3; cs = 0; }
    else { int idx = bid - 2 * nb0; layer = 1; ms = idx & 1; int rest = idx >> 1; rt = rest & 7; g = (rest >> 3) & 15; cs = (rest >> 7) + cs_off; }
    int b = g >> 1, kk = g & 1;
    const float* S = (layer ? (kk ? A2t1 : Et1) : (kk ? A2t0 : Et0)) + (size_t)b * 65536;
    const float* U = layer ? (cs ? (u1s + (size_t)b * 16384) : (cr + (size_t)b * crb))
                           : (u0 + (size_t)b * 16384);
    __shared__ float SL[32][65];
    __shared__ float UL[64][72];
    int r0 = rt * 32;
    int cg = tid & 15, rg = tid >> 4;
    float acc[2][4];
#pragma unroll
    for (int a = 0; a < 2; a++)
#pragma unroll
        for (int c = 0; c < 4; c++) acc[a][c] = 0.f;
    for (int mc = 0; mc < 2; ++mc) {
        int m0 = ms * 128 + mc * 64;
#pragma unroll
        for (int q = 0; q < 2; q++) {
            int idx = q * 256 + tid; int r = idx >> 4, mq = idx & 15;
            float4 v = *(const float4*)&S[(size_t)(r0 + r) * N_ + m0 + mq * 4];
            SL[r][mq * 4 + 0] = v.x; SL[r][mq * 4 + 1] = v.y;
            SL[r][mq * 4 + 2] = v.z; SL[r][mq * 4 + 3] = v.w;
        }
#pragma unroll
        for (int q = 0; q < 4; q++) {
            int idx = q * 256 + tid; int mm = idx >> 4, c4 = idx & 15;
            float4 u = *(const float4*)&U[(size_t)(m0 + mm) * 64 + c4 * 4];
            *(float4*)&UL[mm][c4 * 4] = u;
        }
        __syncthreads();
        for (int mm = 0; mm < 64; ++mm) {
            float4 uv = *(const float4*)&UL[mm][cg * 4];
            float s0 = SL[rg * 2 + 0][mm], s1 = SL[rg * 2 + 1][mm];
            acc[0][0] = fmaf(s0, uv.x, acc[0][0]); acc[0][1] = fmaf(s0, uv.y, acc[0][1]);
            acc[0][2] = fmaf(s0, uv.z, acc[0][2]); acc[0][3] = fmaf(s0, uv.w, acc[0][3]);
            acc[1][0] = fmaf(s1, uv.x, acc[1][0]); acc[1][1] = fmaf(s1, uv.y, acc[1][1]);
            acc[1][2] = fmaf(s1, uv.z, acc[1][2]); acc[1][3] = fmaf(s1, uv.w, acc[1][3]);
        }
        __syncthreads();
    }
#pragma unroll
    for (int a = 0; a < 2; a++) {
        float4 o; o.x = acc[a][0]; o.y = acc[a][1]; o.z = acc[a][2]; o.w = acc[a][3];
        if (layer) *(float4*)&yb1[(size_t)ms * 524288 + ((size_t)g * 256 + r0 + rg * 2 + a) * 128 + cs * 64 + cg * 4] = o;
        else       *(float4*)&yb0[(size_t)ms * 262144 + ((size_t)g * 256 + r0 + rg * 2 + a) * 64 + cg * 4] = o;
    }
}

// ========== merged mm phase + GRU epilogues (32-o slices, sums 2 m-split slots) ====
template <int MODE>
__global__ __launch_bounds__(256) void k_pm(
    const float* NF yb0, const float* NF yb1, const float* NF Y0Xt,
    const float* NF Wl0, const float* NF Bl0, const float* NF Wl1, const float* NF Bl1,
    float* NF u1sa0, float* NF u2sa0, float* NF rb0,
    float* NF u1sa1, float* NF u2sa1, float* NF rb1,
    const float* NF pa, float* NF cw, long cwb, float* NF seq1,
    float* NF hid0, float* NF hid1, int t0, int t1, int nb0)
{
    constexpr int OT = (MODE == 0) ? 128 : 64;
    int bid = blockIdx.x, tid = threadIdx.x;
    int layer, n, os;
    if (bid < nb0) { layer = 0; n = bid & 255; os = bid >> 8; }
    else { int idx = bid - nb0; layer = 1; n = idx & 255; os = idx >> 8; }
    __shared__ float xg[256][12];
    if (layer == 0) {
        int b = tid >> 5, kk = (tid >> 4) & 1, c = (tid & 15) * 4;
        size_t base = (((size_t)(b * 2 + kk)) * 256 + n) * 64 + c;
        float4 v = *(const float4*)&yb0[base];
        float4 w = *(const float4*)&yb0[base + 262144];
        v.x += w.x; v.y += w.y; v.z += w.z; v.w += w.w;
        int j = kk * 66 + 2 + c;
        xg[j + 0][b] = v.x; xg[j + 1][b] = v.y; xg[j + 2][b] = v.z; xg[j + 3][b] = v.w;
        if (tid < 32) {
            int b2 = tid >> 2, k2 = (tid >> 1) & 1, c2 = tid & 1;
            xg[k2 * 66 + c2][b2] = Y0Xt[(((size_t)(b2 * 2 + k2)) * 256 + n) * 2 + c2];
        }
    } else {
        int b = tid >> 5, kk = (tid >> 4) & 1, cq = tid & 15;
#pragma unroll
        for (int q = 0; q < 2; q++) {
            int c = cq * 4 + q * 64;
            size_t base = (((size_t)(b * 2 + kk)) * 256 + n) * 128 + c;
            float4 v = *(const float4*)&yb1[base];
            float4 w = *(const float4*)&yb1[base + 524288];
            v.x += w.x; v.y += w.y; v.z += w.z; v.w += w.w;
            int j = kk * 128 + c;
            xg[j + 0][b] = v.x; xg[j + 1][b] = v.y; xg[j + 2][b] = v.z; xg[j + 3][b] = v.w;
        }
    }
    __syncthreads();
    int J2 = layer ? 256 : 132;
    const float* W = layer ? Wl1 : Wl0;
    const float* Bb = layer ? Bl1 : Bl0;
    int o_l = tid & 31, bg = tid >> 5;      // 8 b per block, 1 per thread
    int o = os * 32 + o_l;
    float acc = Bb[(size_t)n * OT + o];
    const float* Wn = W + (size_t)n * J2 * OT + o;
#pragma unroll 4
    for (int j = 0; j < J2; ++j) {
        float w = Wn[(size_t)j * OT];
        acc = fmaf(xg[j][bg], w, acc);
    }
    {
        int b = bg;
        size_t bn = (size_t)b * 256 + n;
        if (MODE == 0) {
            float v = 1.f / (1.f + __expf(-acc));
            if (layer == 0) {
                if (o < 64) u2sa0[bn * 64 + o] = v * u1sa0[bn * 64 + o];
                else        rb0[bn * 64 + (o - 64)] = v;
            } else {
                if (o < 64) u2sa1[bn * 64 + o] = v * u1sa1[bn * 64 + o];
                else        rb1[bn * 64 + (o - 64)] = v;
            }
        } else {
            float hc = tanhf(acc);
            if (layer == 0) {
                float r = rb0[bn * 64 + o];
                float s = u1sa0[bn * 64 + o];
                float ns = hc + r * (s - hc);
                cw[(size_t)b * cwb + (size_t)n * 64 + o] = ns;
                if (t0 < T_ - 1) u1sa0[bn * 64 + o] = ns + pa[(((size_t)b * T_ + t0 + 1) * 256 + n) * 64 + o];
                else             hid0[bn * 64 + o] = ns;
            } else {
                float r = rb1[bn * 64 + o];
                float s = u1sa1[bn * 64 + o];
                float ns = hc + r * (s - hc);
                seq1[(((size_t)b * T_ + t1) * 256 + n) * 64 + o] = ns;
                if (t1 < T_ - 1) u1sa1[bn * 64 + o] = ns + pa[(((size_t)b * T_ + t1 + 1) * 256 + n) * 64 + o];
                else             hid1[bn * 64 + o] = ns;
            }
        }
    }
}

extern "C" void kernel_launch(void* const* d_in, const int* in_sizes, int n_in,
                              void* d_out, int out_size, void* d_ws, size_t ws_size,
                              hipStream_t stream) {
    const float* x   = (const float*)d_in[0];
    const float* ist = (const float*)d_in[1];
    const float* ne  = (const float*)d_in[2];
    const float* pa  = (const float*)d_in[3];
    const float* gw0 = (const float*)d_in[4];
    const float* gb0 = (const float*)d_in[5];
    const float* uw0 = (const float*)d_in[6];
    const float* ub0 = (const float*)d_in[7];
    const float* gw1 = (const float*)d_in[8];
    const float* gb1 = (const float*)d_in[9];
    const float* uw1 = (const float*)d_in[10];
    const float* ub1 = (const float*)d_in[11];
    float* out = (float*)d_out;
    char*  base = (char*)d_ws;

    float* cur_out = out;                                   // (B,T,N,H)
    float* hid_out = out + (size_t)B_ * T_ * N_ * H_;       // (2,B,N,H)
    float* hid0 = hid_out, * hid1 = hid_out + 131072;

    size_t off = 0;
    auto carve = [&](size_t bytes) { char* p = base + off; off += (bytes + 255) & ~(size_t)255; return p; };
    float* adjw  = (float*)carve(65536ull * 4);
    float* Ebuf  = (float*)carve(6291456ull * 4);
    float* A2    = (float*)carve(6291456ull * 4);
    float* Bg0   = (float*)carve(32768ull * 4);
    float* Bu0   = (float*)carve(16384ull * 4);
    float* Bg1   = (float*)carve(32768ull * 4);
    float* Bu1   = (float*)carve(16384ull * 4);
    float* u1sa0 = (float*)carve(131072ull * 4);
    float* u2sa0 = (float*)carve(131072ull * 4);
    float* rb0   = (float*)carve(131072ull * 4);
    float* u1sa1 = (float*)carve(131072ull * 4);
    float* u2sa1 = (float*)carve(131072ull * 4);
    float* rb1   = (float*)carve(131072ull * 4);
    float* cbuf  = (float*)carve(131072ull * 4);
    float* yb0   = (float*)carve(524288ull * 4);    // 2 m-split slots
    float* yb1   = (float*)carve(1048576ull * 4);   // 2 m-split slots
    float* y0x   = hid1;   // alias: y0x lives in hid1 region until final phase
    size_t common_end = off;
    float* Wg0 = (float*)carve(4325376ull * 4);
    float* Wu0 = (float*)carve(2162688ull * 4);
    float* Wg1 = (float*)carve(8388608ull * 4);
    float* Wu1 = (float*)carve(4194304ull * 4);
    bool pipe = (off <= ws_size);
    if (!pipe) {
        off = common_end;
        float* WgS = (float*)carve(8388608ull * 4);
        float* WuS = (float*)carve(4194304ull * 4);
        if (off > ws_size) { k_sentinel<<<1, 1, 0, stream>>>(out); return; }
        Wg0 = Wg1 = WgS; Wu0 = Wu1 = WuS;
    }

    // ---- time-invariant precompute ----
    k_adj<<<256, 256, 0, stream>>>(ne, adjw);
    k_sub_t<<<dim3(16, 96), 256, 0, stream>>>(pa, Ebuf);
    k_norm<<<96, 1024, 0, stream>>>(Ebuf);
    k_a2<<<dim3(16, 96), 256, 0, stream>>>(adjw, Ebuf, A2);
    k_y0x<<<dim3(4, 192), 256, 0, stream>>>(Ebuf, A2, x, y0x);
    k_bias4<<<256, 192, 0, stream>>>(ne, gb0, ub0, gb1, ub1, Bg0, Bu0, Bg1, Bu1);
    k_init2<<<1024, 256, 0, stream>>>(ist, pa, u1sa0, u1sa1);

    // one super-step: l0 at t0 (if a0), l1 at t1 (if a1)
    auto super = [&](int t0, int t1, bool a0, bool a1, float* cw, long cwb,
                     const float* cr, long crb) {
        const float* Et0  = Ebuf + (size_t)t0 * B_ * 65536;
        const float* A2t0 = A2   + (size_t)t0 * B_ * 65536;
        const float* Et1  = Ebuf + (size_t)t1 * B_ * 65536;
        const float* A2t1 = A2   + (size_t)t1 * B_ * 65536;
        const float* YXt  = y0x  + (size_t)t0 * B_ * 2 * N_ * 2;
        int y0n = a0 ? 128 : 0;                 // l0 (rt,g) blocks per m-slot
        int m0g = a0 ? 1024 : 0, m0u = a0 ? 512 : 0;
        // phase 1: gate-y (l1 both c-halves)
        k_py<<<2 * y0n + (a1 ? 512 : 0), 256, 0, stream>>>(Et0, A2t0, u1sa0, Et1, A2t1, cr, crb, u1sa1, yb0, yb1, y0n, 0);
        // phase 2: gate-mm
        k_pm<0><<<m0g + (a1 ? 1024 : 0), 256, 0, stream>>>(yb0, yb1, YXt, Wg0, Bg0, Wg1, Bg1,
            u1sa0, u2sa0, rb0, u1sa1, u2sa1, rb1, pa, cw, cwb, cur_out, hid0, hid1, t0, t1, m0g);
        // phase 3: upd-y (l1 sa-half only; c-half of yb1 slots unchanged)
        k_py<<<2 * y0n + (a1 ? 256 : 0), 256, 0, stream>>>(Et0, A2t0, u2sa0, Et1, A2t1, cr, crb, u2sa1, yb0, yb1, y0n, 1);
        // phase 4: upd-mm
        k_pm<1><<<m0u + (a1 ? 512 : 0), 256, 0, stream>>>(yb0, yb1, YXt, Wu0, Bu0, Wu1, Bu1,
            u1sa0, u2sa0, rb0, u1sa1, u2sa1, rb1, pa, cw, cwb, cur_out, hid0, hid1, t0, t1, m0u);
    };

    if (pipe) {
        k_wpool4<<<4656, 256, 0, stream>>>(ne, gw0, uw0, gw1, uw1, Wg0, Wu0, Wg1, Wu1);
        for (int s = 0; s <= 12; ++s) {
            bool a0 = (s < 12), a1 = (s >= 1);
            int t0 = a0 ? s : 11, t1 = a1 ? s - 1 : 0;
            super(t0, t1, a0, a1, cbuf, 16384L, cbuf, 16384L);
        }
    } else {
        {
            int t4g = N_ * 132 * 128 / 4, t4u = N_ * 132 * 64 / 4;
            k_wpool<<<(t4g + 255) / 256, 256, 0, stream>>>(ne, gw0, Wg0, 132, 32, t4g);
            k_wpool<<<(t4u + 255) / 256, 256, 0, stream>>>(ne, uw0, Wu0, 132, 16, t4u);
        }
        for (int t = 0; t < T_; ++t)
            super(t, 0, true, false, cur_out + (size_t)t * 16384, (long)T_ * 16384, cbuf, 16384L);
        {
            int t4g = N_ * 256 * 128 / 4, t4u = N_ * 256 * 64 / 4;
            k_wpool<<<(t4g + 255) / 256, 256, 0, stream>>>(ne, gw1, Wg1, 256, 32, t4g);
            k_wpool<<<(t4u + 255) / 256, 256, 0, stream>>>(ne, uw1, Wu1, 256, 16, t4u);
        }
        for (int t = 0; t < T_; ++t)
            super(0, t, false, true, cbuf, 16384L, cur_out + (size_t)t * 16384, (long)T_ * 16384);
    }
    (void)in_sizes; (void)n_in; (void)out_size;
}

// Round 17
// 976.888 us; speedup vs baseline: 2.4557x; 2.4557x over previous
//
#include <hip/hip_runtime.h>
#include <math.h>

// AVWDCRNN round 17 (all-f32). r16 post-mortem: 32-row k_py spilled (VGPR 256,
// 143MB scratch writes/launch) -> 2399us. Revert to r15's proven k_py/k_pm
// (992us); keep ONLY r16's reuse-blocked k_wpool4 (57 -> ~28us).

#define NF __restrict__
constexpr int N_ = 256, B_ = 8, T_ = 12, H_ = 64, E_ = 16;

__global__ void k_sentinel(float* NF out) { out[0] = 1.0e6f; }

// ---------------- adj = softmax(relu(ne ne^T), axis=1) ----------------
__global__ void k_adj(const float* NF ne, float* NF adj) {
    int n = blockIdx.x, m = threadIdx.x;
    __shared__ float en[E_];
    __shared__ float red[256];
    if (m < E_) en[m] = ne[n * E_ + m];
    __syncthreads();
    float s = 0.f;
#pragma unroll
    for (int d = 0; d < E_; d++) s += en[d] * ne[m * E_ + d];
    s = fmaxf(s, 0.f);
    red[m] = s; __syncthreads();
    for (int st = 128; st > 0; st >>= 1) { if (m < st) red[m] = fmaxf(red[m], red[m + st]); __syncthreads(); }
    float mx = red[0]; __syncthreads();
    float e = __expf(s - mx);
    red[m] = e; __syncthreads();
    for (int st = 128; st > 0; st >>= 1) { if (m < st) red[m] += red[m + st]; __syncthreads(); }
    adj[(size_t)n * N_ + m] = e / red[0];
}

// ------------- all four biases in one launch -------------
__global__ void k_bias4(const float* NF ne, const float* NF gb0, const float* NF ub0,
                        const float* NF gb1, const float* NF ub1,
                        float* NF Bg0, float* NF Bu0, float* NF Bg1, float* NF Bu1) {
    int n = blockIdx.x, tid = threadIdx.x;
    __shared__ float e[E_];
    if (tid < E_) e[tid] = ne[n * E_ + tid];
    __syncthreads();
    if (tid < 128) {
        float a0 = 0.f, a1 = 0.f;
#pragma unroll
        for (int d = 0; d < E_; d++) { a0 = fmaf(e[d], gb0[d * 128 + tid], a0); a1 = fmaf(e[d], gb1[d * 128 + tid], a1); }
        Bg0[(size_t)n * 128 + tid] = a0; Bg1[(size_t)n * 128 + tid] = a1;
    } else {
        int o = tid - 128;
        float a0 = 0.f, a1 = 0.f;
#pragma unroll
        for (int d = 0; d < E_; d++) { a0 = fmaf(e[d], ub0[d * 64 + o], a0); a1 = fmaf(e[d], ub1[d * 64 + o], a1); }
        Bu0[(size_t)n * 64 + o] = a0; Bu1[(size_t)n * 64 + o] = a1;
    }
}

// ------------- single-buffer W pool (fallback tier) -------------
__global__ void k_wpool(const float* NF ne, const float* NF wp, float* NF W,
                        int I2, int O4, int total4) {
    int idx4 = blockIdx.x * 256 + threadIdx.x;
    if (idx4 >= total4) return;
    int o4 = idx4 % O4; int rem = idx4 / O4; int j = rem % I2; int n = rem / I2;
    const float* nrow = ne + n * E_;
    float ax = 0.f, ay = 0.f, az = 0.f, aw = 0.f;
#pragma unroll
    for (int d = 0; d < E_; d++) {
        float e = nrow[d];
        const float4 w = *(const float4*)&wp[(((size_t)d * I2 + j) * O4 + o4) * 4];
        ax = fmaf(e, w.x, ax); ay = fmaf(e, w.y, ay); az = fmaf(e, w.z, az); aw = fmaf(e, w.w, aw);
    }
    float4 r; r.x = ax; r.y = ay; r.z = az; r.w = aw;
    *(float4*)&W[(size_t)idx4 * 4] = r;
}

// ------------- all 4 W pools: reuse-blocked (64 col4 x 16 nodes/block) -------------
__global__ __launch_bounds__(256) void k_wpool4(const float* NF ne,
                         const float* NF gw0, const float* NF uw0,
                         const float* NF gw1, const float* NF uw1,
                         float* NF Wg0, float* NF Wu0, float* NF Wg1, float* NF Wu1) {
    int cb = blockIdx.x % 291, nb = blockIdx.x / 291;
    const float* wp; float* W; int O4, c0;
    if (cb < 66)       { wp = gw0; W = Wg0; O4 = 4224; c0 = cb * 64; }
    else if (cb < 99)  { wp = uw0; W = Wu0; O4 = 2112; c0 = (cb - 66) * 64; }
    else if (cb < 227) { wp = gw1; W = Wg1; O4 = 8192; c0 = (cb - 99) * 64; }
    else               { wp = uw1; W = Wu1; O4 = 4096; c0 = (cb - 227) * 64; }
    __shared__ float4 PL[16][64];    // pool chunk: 16 d x 64 col4 (16 KB)
    __shared__ float  eL[16][17];
    int tid = threadIdx.x;
#pragma unroll
    for (int q = 0; q < 4; q++) {
        int idx = q * 256 + tid; int d = idx >> 6, c = idx & 63;
        PL[d][c] = *(const float4*)&wp[((size_t)d * O4 + c0 + c) * 4];
    }
    int n0 = nb * 16;
    { int nn = tid >> 4, d = tid & 15; eL[nn][d] = ne[(n0 + nn) * E_ + d]; }
    __syncthreads();
    int c = tid & 63, ng = tid >> 6;
#pragma unroll
    for (int q = 0; q < 4; q++) {
        int nn = ng * 4 + q;
        float ax = 0.f, ay = 0.f, az = 0.f, aw = 0.f;
#pragma unroll
        for (int d = 0; d < E_; d++) {
            float e = eL[nn][d];
            float4 w = PL[d][c];
            ax = fmaf(e, w.x, ax); ay = fmaf(e, w.y, ay);
            az = fmaf(e, w.z, az); aw = fmaf(e, w.w, aw);
        }
        float4 r; r.x = ax; r.y = ay; r.z = az; r.w = aw;
        *(float4*)&W[((size_t)(n0 + nn) * O4 + c0 + c) * 4] = r;
    }
}

// ------------- E[tb,i,j] = exp(-L1(pa_i, pa_j)) ; tiled 64x64 -------------
__global__ __launch_bounds__(256) void k_sub_t(const float* NF pa, float* NF Ebuf) {
    int bx = blockIdx.x, tb = blockIdx.y;    // grid (16, 96)
    int it = bx & 3, jt = bx >> 2;
    int t = tb / B_, b = tb % B_;
    const float* p = pa + ((size_t)b * T_ + t) * N_ * H_;
    __shared__ float piT[64][64];
    __shared__ float pjT[64][64];
    int tid = threadIdx.x;
    int i0 = it * 64, j0 = jt * 64;
#pragma unroll
    for (int q = 0; q < 4; q++) {
        int idx = q * 256 + tid; int hq = idx & 15, i = idx >> 4;
        float4 v = *(const float4*)&p[(size_t)(i0 + i) * 64 + hq * 4];
        piT[hq * 4 + 0][i] = v.x; piT[hq * 4 + 1][i] = v.y; piT[hq * 4 + 2][i] = v.z; piT[hq * 4 + 3][i] = v.w;
        float4 w = *(const float4*)&p[(size_t)(j0 + i) * 64 + hq * 4];
        pjT[hq * 4 + 0][i] = w.x; pjT[hq * 4 + 1][i] = w.y; pjT[hq * 4 + 2][i] = w.z; pjT[hq * 4 + 3][i] = w.w;
    }
    __syncthreads();
    int jg = tid & 15, ig = tid >> 4;
    float acc[4][4];
#pragma unroll
    for (int a = 0; a < 4; a++)
#pragma unroll
        for (int c = 0; c < 4; c++) acc[a][c] = 0.f;
    for (int h = 0; h < 64; h++) {
        float4 a4 = *(const float4*)&piT[h][ig * 4];
        float4 b4 = *(const float4*)&pjT[h][jg * 4];
        float av[4] = { a4.x, a4.y, a4.z, a4.w };
        float bv[4] = { b4.x, b4.y, b4.z, b4.w };
#pragma unroll
        for (int a = 0; a < 4; a++)
#pragma unroll
            for (int c = 0; c < 4; c++) acc[a][c] += fabsf(av[a] - bv[c]);
    }
    float* dst = Ebuf + (size_t)tb * N_ * N_;
#pragma unroll
    for (int a = 0; a < 4; a++) {
        float4 o; o.x = __expf(-acc[a][0]); o.y = __expf(-acc[a][1]);
        o.z = __expf(-acc[a][2]); o.w = __expf(-acc[a][3]);
        *(float4*)&dst[(size_t)(i0 + ig * 4 + a) * N_ + j0 + jg * 4] = o;
    }
}

// ------------- column softmax normalize in-place -------------
__global__ void k_norm(float* NF Ebuf) {
    int tb = blockIdx.x, tid = threadIdx.x;   // 96 x 1024
    int j = tid & 255, q = tid >> 8;
    float* s = Ebuf + (size_t)tb * 65536;
    __shared__ float red[4][256];
    float S = 0.f;
    for (int i = q * 64; i < q * 64 + 64; ++i) S += s[(size_t)i * N_ + j];
    red[q][j] = S; __syncthreads();
    float inv = 1.f / (red[0][j] + red[1][j] + red[2][j] + red[3][j]);
    for (int i = q * 64; i < q * 64 + 64; ++i) s[(size_t)i * N_ + j] *= inv;
}

// ------------- A2[tb] = adj @ E'[tb]  (64x64 out-tiles, 32-m chunks) -------------
__global__ __launch_bounds__(256) void k_a2(const float* NF adjm, const float* NF Ebuf, float* NF A2) {
    int rt = blockIdx.x & 3, ct = blockIdx.x >> 2;   // grid (16, 96)
    int tb = blockIdx.y;
    const float* U = Ebuf + (size_t)tb * N_ * N_;
    int r0 = rt * 64, c0 = ct * 64;
    __shared__ float SL[64][33];
    __shared__ float UL[32][72];
    int tid = threadIdx.x, cg = tid & 15, rg = tid >> 4;
    float acc[4][4];
#pragma unroll
    for (int a = 0; a < 4; a++)
#pragma unroll
        for (int c = 0; c < 4; c++) acc[a][c] = 0.f;
    for (int mc = 0; mc < 8; ++mc) {
        int m0 = mc * 32;
#pragma unroll
        for (int q = 0; q < 2; q++) {
            int idx = q * 256 + tid;
            int r = idx >> 3, mq = idx & 7;
            float4 v = *(const float4*)&adjm[(size_t)(r0 + r) * N_ + m0 + mq * 4];
            SL[r][mq * 4 + 0] = v.x; SL[r][mq * 4 + 1] = v.y;
            SL[r][mq * 4 + 2] = v.z; SL[r][mq * 4 + 3] = v.w;
            int mm = idx >> 4, c4 = idx & 15;
            float4 u = *(const float4*)&U[(size_t)(m0 + mm) * N_ + c0 + c4 * 4];
            *(float4*)&UL[mm][c4 * 4] = u;
        }
        __syncthreads();
        for (int mm = 0; mm < 32; ++mm) {
            float4 uv = *(const float4*)&UL[mm][cg * 4];
            float sv[4];
#pragma unroll
            for (int a = 0; a < 4; a++) sv[a] = SL[rg * 4 + a][mm];
#pragma unroll
            for (int a = 0; a < 4; a++) {
                acc[a][0] = fmaf(sv[a], uv.x, acc[a][0]);
                acc[a][1] = fmaf(sv[a], uv.y, acc[a][1]);
                acc[a][2] = fmaf(sv[a], uv.z, acc[a][2]);
                acc[a][3] = fmaf(sv[a], uv.w, acc[a][3]);
            }
        }
        __syncthreads();
    }
    float* dst = A2 + (size_t)tb * N_ * N_;
#pragma unroll
    for (int a = 0; a < 4; a++) {
        float4 o; o.x = acc[a][0]; o.y = acc[a][1]; o.z = acc[a][2]; o.w = acc[a][3];
        *(float4*)&dst[(size_t)(r0 + rg * 4 + a) * N_ + c0 + cg * 4] = o;
    }
}

// ------------- Y0X = S'_k @ x  (64-row tiles, 4-way m-split + shfl) -------------
__global__ __launch_bounds__(256) void k_y0x(const float* NF Ebuf, const float* NF A2,
                                             const float* NF x, float* NF y0x) {
    int rt = blockIdx.x, tbk = blockIdx.y;   // grid (4, 192)
    int tb = tbk >> 1, kk = tbk & 1;
    int t = tb / B_, b = tb % B_;
    const float* S = (kk ? A2 : Ebuf) + (size_t)tb * N_ * N_;
    const float* xb = x + ((size_t)b * T_ + t) * N_ * 2;
    __shared__ float SL[64][65];
    __shared__ float xw[64][2];
    int tid = threadIdx.x, rg = tid >> 2, mg = tid & 3;
    int r0 = rt * 64;
    float a0 = 0.f, a1 = 0.f;
    for (int mc = 0; mc < 4; ++mc) {
        int m0 = mc * 64;
#pragma unroll
        for (int q = 0; q < 4; q++) {
            int idx = q * 256 + tid; int r = idx >> 4, mq = idx & 15;
            float4 v = *(const float4*)&S[(size_t)(r0 + r) * N_ + m0 + mq * 4];
            SL[r][mq * 4 + 0] = v.x; SL[r][mq * 4 + 1] = v.y;
            SL[r][mq * 4 + 2] = v.z; SL[r][mq * 4 + 3] = v.w;
        }
        if (tid < 128) xw[tid >> 1][tid & 1] = xb[(size_t)(m0 + (tid >> 1)) * 2 + (tid & 1)];
        __syncthreads();
        for (int mm = mg * 16; mm < mg * 16 + 16; ++mm) {
            float s = SL[rg][mm];
            a0 = fmaf(s, xw[mm][0], a0); a1 = fmaf(s, xw[mm][1], a1);
        }
        __syncthreads();
    }
    a0 += __shfl_xor(a0, 1); a0 += __shfl_xor(a0, 2);
    a1 += __shfl_xor(a1, 1); a1 += __shfl_xor(a1, 2);
    if (mg == 0) {
        y0x[(((size_t)tb * 2 + kk) * N_ + r0 + rg) * 2 + 0] = a0;
        y0x[(((size_t)tb * 2 + kk) * N_ + r0 + rg) * 2 + 1] = a1;
    }
}

// ------------- sa init for both layers -------------
__global__ void k_init2(const float* NF ist, const float* NF pa,
                        float* NF u1sa0, float* NF u1sa1) {
    int idx = blockIdx.x * 256 + threadIdx.x;   // 262144
    int l = idx >> 17, r = idx & 131071;
    int b = r >> 14, rem = r & 16383;
    float v = ist[(size_t)l * 131072 + r] + pa[(size_t)b * T_ * 16384 + rem];
    if (l == 0) u1sa0[r] = v; else u1sa1[r] = v;
}

// ========== merged y phase, 2-way m-split (r15 proven body) ==========
__global__ __launch_bounds__(256) void k_py(
    const float* NF Et0, const float* NF A2t0, const float* NF u0,
    const float* NF Et1, const float* NF A2t1, const float* NF cr, long crb,
    const float* NF u1s, float* NF yb0, float* NF yb1, int nb0, int cs_off)
{
    int bid = blockIdx.x, tid = threadIdx.x;
    int layer, rt, g, cs, ms;
    if (bid < 2 * nb0) { layer = 0; ms = bid & 1; int rest = bid >> 1; rt = rest & 3; g = rest >> 2; cs = 0; }
    else { int idx = bid - 2 * nb0; layer = 1; ms = idx & 1; int rest = idx >> 1; rt = rest & 3; g = (rest >> 2) & 15; cs = (rest >> 6) + cs_off; }
    int b = g >> 1, kk = g & 1;
    const float* S = (layer ? (kk ? A2t1 : Et1) : (kk ? A2t0 : Et0)) + (size_t)b * 65536;
    const float* U = layer ? (cs ? (u1s + (size_t)b * 16384) : (cr + (size_t)b * crb))
                           : (u0 + (size_t)b * 16384);
    __shared__ float SL[64][65];
    __shared__ float UL[64][72];
    int r0 = rt * 64;
    int cg = tid & 15, rg = tid >> 4;
    float acc[4][4];
#pragma unroll
    for (int a = 0; a < 4; a++)
#pragma unroll
        for (int c = 0; c < 4; c++) acc[a][c] = 0.f;
    for (int mc = 0; mc < 2; ++mc) {
        int m0 = ms * 128 + mc * 64;
#pragma unroll
        for (int q = 0; q < 4; q++) {
            int idx = q * 256 + tid; int r = idx >> 4, mq = idx & 15;
            float4 v = *(const float4*)&S[(size_t)(r0 + r) * N_ + m0 + mq * 4];
            SL[r][mq * 4 + 0] = v.x; SL[r][mq * 4 + 1] = v.y;
            SL[r][mq * 4 + 2] = v.z; SL[r][mq * 4 + 3] = v.w;
            float4 u = *(const float4*)&U[(size_t)(m0 + r) * 64 + mq * 4];
            *(float4*)&UL[r][mq * 4] = u;
        }
        __syncthreads();
        for (int mm = 0; mm < 64; ++mm) {
            float4 uv = *(const float4*)&UL[mm][cg * 4];
            float sv[4];
#pragma unroll
            for (int a = 0; a < 4; a++) sv[a] = SL[rg * 4 + a][mm];
#pragma unroll
            for (int a = 0; a < 4; a++) {
                acc[a][0] = fmaf(sv[a], uv.x, acc[a][0]);
                acc[a][1] = fmaf(sv[a], uv.y, acc[a][1]);
                acc[a][2] = fmaf(sv[a], uv.z, acc[a][2]);
                acc[a][3] = fmaf(sv[a], uv.w, acc[a][3]);
            }
        }
        __syncthreads();
    }
#pragma unroll
    for (int a = 0; a < 4; a++) {
        float4 o; o.x = acc[a][0]; o.y = acc[a][1]; o.z = acc[a][2]; o.w = acc[a][3];
        if (layer) *(float4*)&yb1[(size_t)ms * 524288 + ((size_t)g * 256 + r0 + rg * 4 + a) * 128 + cs * 64 + cg * 4] = o;
        else       *(float4*)&yb0[(size_t)ms * 262144 + ((size_t)g * 256 + r0 + rg * 4 + a) * 64 + cg * 4] = o;
    }
}

// ========== merged mm phase + GRU epilogues (r15 proven body) ==========
template <int MODE>
__global__ __launch_bounds__(256) void k_pm(
    const float* NF yb0, const float* NF yb1, const float* NF Y0Xt,
    const float* NF Wl0, const float* NF Bl0, const float* NF Wl1, const float* NF Bl1,
    float* NF u1sa0, float* NF u2sa0, float* NF rb0,
    float* NF u1sa1, float* NF u2sa1, float* NF rb1,
    const float* NF pa, float* NF cw, long cwb, float* NF seq1,
    float* NF hid0, float* NF hid1, int t0, int t1, int nb0)
{
    constexpr int OT = (MODE == 0) ? 128 : 64;
    int bid = blockIdx.x, tid = threadIdx.x;
    int layer, n, os;
    if (bid < nb0) { layer = 0; n = bid & 255; os = bid >> 8; }
    else { int idx = bid - nb0; layer = 1; n = idx & 255; os = idx >> 8; }
    __shared__ float xg[256][12];
    if (layer == 0) {
        int b = tid >> 5, kk = (tid >> 4) & 1, c = (tid & 15) * 4;
        size_t base = (((size_t)(b * 2 + kk)) * 256 + n) * 64 + c;
        float4 v = *(const float4*)&yb0[base];
        float4 w = *(const float4*)&yb0[base + 262144];
        v.x += w.x; v.y += w.y; v.z += w.z; v.w += w.w;
        int j = kk * 66 + 2 + c;
        xg[j + 0][b] = v.x; xg[j + 1][b] = v.y; xg[j + 2][b] = v.z; xg[j + 3][b] = v.w;
        if (tid < 32) {
            int b2 = tid >> 2, k2 = (tid >> 1) & 1, c2 = tid & 1;
            xg[k2 * 66 + c2][b2] = Y0Xt[(((size_t)(b2 * 2 + k2)) * 256 + n) * 2 + c2];
        }
    } else {
        int b = tid >> 5, kk = (tid >> 4) & 1, cq = tid & 15;
#pragma unroll
        for (int q = 0; q < 2; q++) {
            int c = cq * 4 + q * 64;
            size_t base = (((size_t)(b * 2 + kk)) * 256 + n) * 128 + c;
            float4 v = *(const float4*)&yb1[base];
            float4 w = *(const float4*)&yb1[base + 524288];
            v.x += w.x; v.y += w.y; v.z += w.z; v.w += w.w;
            int j = kk * 128 + c;
            xg[j + 0][b] = v.x; xg[j + 1][b] = v.y; xg[j + 2][b] = v.z; xg[j + 3][b] = v.w;
        }
    }
    __syncthreads();
    int J2 = layer ? 256 : 132;
    const float* W = layer ? Wl1 : Wl0;
    const float* Bb = layer ? Bl1 : Bl0;
    int o_l = tid & 63, bg = tid >> 6;
    int o = os * 64 + o_l;
    float bias = Bb[(size_t)n * OT + o];
    float acc0 = bias, acc1 = bias;
    const float* Wn = W + (size_t)n * J2 * OT + o;
#pragma unroll 4
    for (int j = 0; j < J2; ++j) {
        float w = Wn[(size_t)j * OT];
        float2 xv = *(const float2*)&xg[j][bg * 2];
        acc0 = fmaf(xv.x, w, acc0); acc1 = fmaf(xv.y, w, acc1);
    }
#pragma unroll
    for (int q = 0; q < 2; ++q) {
        int b = bg * 2 + q;
        float a = q ? acc1 : acc0;
        size_t bn = (size_t)b * 256 + n;
        if (MODE == 0) {
            float v = 1.f / (1.f + __expf(-a));
            if (layer == 0) {
                if (o < 64) u2sa0[bn * 64 + o] = v * u1sa0[bn * 64 + o];
                else        rb0[bn * 64 + (o - 64)] = v;
            } else {
                if (o < 64) u2sa1[bn * 64 + o] = v * u1sa1[bn * 64 + o];
                else        rb1[bn * 64 + (o - 64)] = v;
            }
        } else {
            float hc = tanhf(a);
            if (layer == 0) {
                float r = rb0[bn * 64 + o];
                float s = u1sa0[bn * 64 + o];
                float ns = hc + r * (s - hc);
                cw[(size_t)b * cwb + (size_t)n * 64 + o] = ns;
                if (t0 < T_ - 1) u1sa0[bn * 64 + o] = ns + pa[(((size_t)b * T_ + t0 + 1) * 256 + n) * 64 + o];
                else             hid0[bn * 64 + o] = ns;
            } else {
                float r = rb1[bn * 64 + o];
                float s = u1sa1[bn * 64 + o];
                float ns = hc + r * (s - hc);
                seq1[(((size_t)b * T_ + t1) * 256 + n) * 64 + o] = ns;
                if (t1 < T_ - 1) u1sa1[bn * 64 + o] = ns + pa[(((size_t)b * T_ + t1 + 1) * 256 + n) * 64 + o];
                else             hid1[bn * 64 + o] = ns;
            }
        }
    }
}

extern "C" void kernel_launch(void* const* d_in, const int* in_sizes, int n_in,
                              void* d_out, int out_size, void* d_ws, size_t ws_size,
                              hipStream_t stream) {
    const float* x   = (const float*)d_in[0];
    const float* ist = (const float*)d_in[1];
    const float* ne  = (const float*)d_in[2];
    const float* pa  = (const float*)d_in[3];
    const float* gw0 = (const float*)d_in[4];
    const float* gb0 = (const float*)d_in[5];
    const float* uw0 = (const float*)d_in[6];
    const float* ub0 = (const float*)d_in[7];
    const float* gw1 = (const float*)d_in[8];
    const float* gb1 = (const float*)d_in[9];
    const float* uw1 = (const float*)d_in[10];
    const float* ub1 = (const float*)d_in[11];
    float* out = (float*)d_out;
    char*  base = (char*)d_ws;

    float* cur_out = out;                                   // (B,T,N,H)
    float* hid_out = out + (size_t)B_ * T_ * N_ * H_;       // (2,B,N,H)
    float* hid0 = hid_out, * hid1 = hid_out + 131072;

    size_t off = 0;
    auto carve = [&](size_t bytes) { char* p = base + off; off += (bytes + 255) & ~(size_t)255; return p; };
    float* adjw  = (float*)carve(65536ull * 4);
    float* Ebuf  = (float*)carve(6291456ull * 4);
    float* A2    = (float*)carve(6291456ull * 4);
    float* Bg0   = (float*)carve(32768ull * 4);
    float* Bu0   = (float*)carve(16384ull * 4);
    float* Bg1   = (float*)carve(32768ull * 4);
    float* Bu1   = (float*)carve(16384ull * 4);
    float* u1sa0 = (float*)carve(131072ull * 4);
    float* u2sa0 = (float*)carve(131072ull * 4);
    float* rb0   = (float*)carve(131072ull * 4);
    float* u1sa1 = (float*)carve(131072ull * 4);
    float* u2sa1 = (float*)carve(131072ull * 4);
    float* rb1   = (float*)carve(131072ull * 4);
    float* cbuf  = (float*)carve(131072ull * 4);
    float* yb0   = (float*)carve(524288ull * 4);    // 2 m-split slots
    float* yb1   = (float*)carve(1048576ull * 4);   // 2 m-split slots
    float* y0x   = hid1;   // alias: y0x lives in hid1 region until final phase
    size_t common_end = off;
    float* Wg0 = (float*)carve(4325376ull * 4);
    float* Wu0 = (float*)carve(2162688ull * 4);
    float* Wg1 = (float*)carve(8388608ull * 4);
    float* Wu1 = (float*)carve(4194304ull * 4);
    bool pipe = (off <= ws_size);
    if (!pipe) {
        off = common_end;
        float* WgS = (float*)carve(8388608ull * 4);
        float* WuS = (float*)carve(4194304ull * 4);
        if (off > ws_size) { k_sentinel<<<1, 1, 0, stream>>>(out); return; }
        Wg0 = Wg1 = WgS; Wu0 = Wu1 = WuS;
    }

    // ---- time-invariant precompute ----
    k_adj<<<256, 256, 0, stream>>>(ne, adjw);
    k_sub_t<<<dim3(16, 96), 256, 0, stream>>>(pa, Ebuf);
    k_norm<<<96, 1024, 0, stream>>>(Ebuf);
    k_a2<<<dim3(16, 96), 256, 0, stream>>>(adjw, Ebuf, A2);
    k_y0x<<<dim3(4, 192), 256, 0, stream>>>(Ebuf, A2, x, y0x);
    k_bias4<<<256, 192, 0, stream>>>(ne, gb0, ub0, gb1, ub1, Bg0, Bu0, Bg1, Bu1);
    k_init2<<<1024, 256, 0, stream>>>(ist, pa, u1sa0, u1sa1);

    // one super-step: l0 at t0 (if a0), l1 at t1 (if a1)
    auto super = [&](int t0, int t1, bool a0, bool a1, float* cw, long cwb,
                     const float* cr, long crb) {
        const float* Et0  = Ebuf + (size_t)t0 * B_ * 65536;
        const float* A2t0 = A2   + (size_t)t0 * B_ * 65536;
        const float* Et1  = Ebuf + (size_t)t1 * B_ * 65536;
        const float* A2t1 = A2   + (size_t)t1 * B_ * 65536;
        const float* YXt  = y0x  + (size_t)t0 * B_ * 2 * N_ * 2;
        int y0n = a0 ? 64 : 0;
        int m0g = a0 ? 512 : 0, m0u = a0 ? 256 : 0;
        k_py<<<2 * y0n + (a1 ? 256 : 0), 256, 0, stream>>>(Et0, A2t0, u1sa0, Et1, A2t1, cr, crb, u1sa1, yb0, yb1, y0n, 0);
        k_pm<0><<<m0g + (a1 ? 512 : 0), 256, 0, stream>>>(yb0, yb1, YXt, Wg0, Bg0, Wg1, Bg1,
            u1sa0, u2sa0, rb0, u1sa1, u2sa1, rb1, pa, cw, cwb, cur_out, hid0, hid1, t0, t1, m0g);
        k_py<<<2 * y0n + (a1 ? 128 : 0), 256, 0, stream>>>(Et0, A2t0, u2sa0, Et1, A2t1, cr, crb, u2sa1, yb0, yb1, y0n, 1);
        k_pm<1><<<m0u + (a1 ? 256 : 0), 256, 0, stream>>>(yb0, yb1, YXt, Wu0, Bu0, Wu1, Bu1,
            u1sa0, u2sa0, rb0, u1sa1, u2sa1, rb1, pa, cw, cwb, cur_out, hid0, hid1, t0, t1, m0u);
    };

    if (pipe) {
        k_wpool4<<<4656, 256, 0, stream>>>(ne, gw0, uw0, gw1, uw1, Wg0, Wu0, Wg1, Wu1);
        for (int s = 0; s <= 12; ++s) {
            bool a0 = (s < 12), a1 = (s >= 1);
            int t0 = a0 ? s : 11, t1 = a1 ? s - 1 : 0;
            super(t0, t1, a0, a1, cbuf, 16384L, cbuf, 16384L);
        }
    } else {
        {
            int t4g = N_ * 132 * 128 / 4, t4u = N_ * 132 * 64 / 4;
            k_wpool<<<(t4g + 255) / 256, 256, 0, stream>>>(ne, gw0, Wg0, 132, 32, t4g);
            k_wpool<<<(t4u + 255) / 256, 256, 0, stream>>>(ne, uw0, Wu0, 132, 16, t4u);
        }
        for (int t = 0; t < T_; ++t)
            super(t, 0, true, false, cur_out + (size_t)t * 16384, (long)T_ * 16384, cbuf, 16384L);
        {
            int t4g = N_ * 256 * 128 / 4, t4u = N_ * 256 * 64 / 4;
            k_wpool<<<(t4g + 255) / 256, 256, 0, stream>>>(ne, gw1, Wg1, 256, 32, t4g);
            k_wpool<<<(t4u + 255) / 256, 256, 0, stream>>>(ne, uw1, Wu1, 256, 16, t4u);
        }
        for (int t = 0; t < T_; ++t)
            super(0, t, false, true, cbuf, 16384L, cur_out + (size_t)t * 16384, (long)T_ * 16384);
    }
    (void)in_sizes; (void)n_in; (void)out_size;
}

// Round 18
// 783.067 us; speedup vs baseline: 3.0635x; 1.2475x over previous
//
#include <hip/hip_runtime.h>
#include <math.h>

// AVWDCRNN round 18 (all-f32). r17=977us (best). Single controlled change:
// k_pm W-stream j-loop unroll 4 -> 8 (double in-flight loads). Tests whether
// the steady mm phase is latency-bound (expect -70us) or BW-bound (neutral,
// which would pin the steady-state at its memory ceiling).

#define NF __restrict__
constexpr int N_ = 256, B_ = 8, T_ = 12, H_ = 64, E_ = 16;

__global__ void k_sentinel(float* NF out) { out[0] = 1.0e6f; }

// ---------------- adj = softmax(relu(ne ne^T), axis=1) ----------------
__global__ void k_adj(const float* NF ne, float* NF adj) {
    int n = blockIdx.x, m = threadIdx.x;
    __shared__ float en[E_];
    __shared__ float red[256];
    if (m < E_) en[m] = ne[n * E_ + m];
    __syncthreads();
    float s = 0.f;
#pragma unroll
    for (int d = 0; d < E_; d++) s += en[d] * ne[m * E_ + d];
    s = fmaxf(s, 0.f);
    red[m] = s; __syncthreads();
    for (int st = 128; st > 0; st >>= 1) { if (m < st) red[m] = fmaxf(red[m], red[m + st]); __syncthreads(); }
    float mx = red[0]; __syncthreads();
    float e = __expf(s - mx);
    red[m] = e; __syncthreads();
    for (int st = 128; st > 0; st >>= 1) { if (m < st) red[m] += red[m + st]; __syncthreads(); }
    adj[(size_t)n * N_ + m] = e / red[0];
}

// ------------- all four biases in one launch -------------
__global__ void k_bias4(const float* NF ne, const float* NF gb0, const float* NF ub0,
                        const float* NF gb1, const float* NF ub1,
                        float* NF Bg0, float* NF Bu0, float* NF Bg1, float* NF Bu1) {
    int n = blockIdx.x, tid = threadIdx.x;
    __shared__ float e[E_];
    if (tid < E_) e[tid] = ne[n * E_ + tid];
    __syncthreads();
    if (tid < 128) {
        float a0 = 0.f, a1 = 0.f;
#pragma unroll
        for (int d = 0; d < E_; d++) { a0 = fmaf(e[d], gb0[d * 128 + tid], a0); a1 = fmaf(e[d], gb1[d * 128 + tid], a1); }
        Bg0[(size_t)n * 128 + tid] = a0; Bg1[(size_t)n * 128 + tid] = a1;
    } else {
        int o = tid - 128;
        float a0 = 0.f, a1 = 0.f;
#pragma unroll
        for (int d = 0; d < E_; d++) { a0 = fmaf(e[d], ub0[d * 64 + o], a0); a1 = fmaf(e[d], ub1[d * 64 + o], a1); }
        Bu0[(size_t)n * 64 + o] = a0; Bu1[(size_t)n * 64 + o] = a1;
    }
}

// ------------- single-buffer W pool (fallback tier) -------------
__global__ void k_wpool(const float* NF ne, const float* NF wp, float* NF W,
                        int I2, int O4, int total4) {
    int idx4 = blockIdx.x * 256 + threadIdx.x;
    if (idx4 >= total4) return;
    int o4 = idx4 % O4; int rem = idx4 / O4; int j = rem % I2; int n = rem / I2;
    const float* nrow = ne + n * E_;
    float ax = 0.f, ay = 0.f, az = 0.f, aw = 0.f;
#pragma unroll
    for (int d = 0; d < E_; d++) {
        float e = nrow[d];
        const float4 w = *(const float4*)&wp[(((size_t)d * I2 + j) * O4 + o4) * 4];
        ax = fmaf(e, w.x, ax); ay = fmaf(e, w.y, ay); az = fmaf(e, w.z, az); aw = fmaf(e, w.w, aw);
    }
    float4 r; r.x = ax; r.y = ay; r.z = az; r.w = aw;
    *(float4*)&W[(size_t)idx4 * 4] = r;
}

// ------------- all 4 W pools: reuse-blocked (64 col4 x 16 nodes/block) -------------
__global__ __launch_bounds__(256) void k_wpool4(const float* NF ne,
                         const float* NF gw0, const float* NF uw0,
                         const float* NF gw1, const float* NF uw1,
                         float* NF Wg0, float* NF Wu0, float* NF Wg1, float* NF Wu1) {
    int cb = blockIdx.x % 291, nb = blockIdx.x / 291;
    const float* wp; float* W; int O4, c0;
    if (cb < 66)       { wp = gw0; W = Wg0; O4 = 4224; c0 = cb * 64; }
    else if (cb < 99)  { wp = uw0; W = Wu0; O4 = 2112; c0 = (cb - 66) * 64; }
    else if (cb < 227) { wp = gw1; W = Wg1; O4 = 8192; c0 = (cb - 99) * 64; }
    else               { wp = uw1; W = Wu1; O4 = 4096; c0 = (cb - 227) * 64; }
    __shared__ float4 PL[16][64];
    __shared__ float  eL[16][17];
    int tid = threadIdx.x;
#pragma unroll
    for (int q = 0; q < 4; q++) {
        int idx = q * 256 + tid; int d = idx >> 6, c = idx & 63;
        PL[d][c] = *(const float4*)&wp[((size_t)d * O4 + c0 + c) * 4];
    }
    int n0 = nb * 16;
    { int nn = tid >> 4, d = tid & 15; eL[nn][d] = ne[(n0 + nn) * E_ + d]; }
    __syncthreads();
    int c = tid & 63, ng = tid >> 6;
#pragma unroll
    for (int q = 0; q < 4; q++) {
        int nn = ng * 4 + q;
        float ax = 0.f, ay = 0.f, az = 0.f, aw = 0.f;
#pragma unroll
        for (int d = 0; d < E_; d++) {
            float e = eL[nn][d];
            float4 w = PL[d][c];
            ax = fmaf(e, w.x, ax); ay = fmaf(e, w.y, ay);
            az = fmaf(e, w.z, az); aw = fmaf(e, w.w, aw);
        }
        float4 r; r.x = ax; r.y = ay; r.z = az; r.w = aw;
        *(float4*)&W[((size_t)(n0 + nn) * O4 + c0 + c) * 4] = r;
    }
}

// ------------- E[tb,i,j] = exp(-L1(pa_i, pa_j)) ; tiled 64x64 -------------
__global__ __launch_bounds__(256) void k_sub_t(const float* NF pa, float* NF Ebuf) {
    int bx = blockIdx.x, tb = blockIdx.y;    // grid (16, 96)
    int it = bx & 3, jt = bx >> 2;
    int t = tb / B_, b = tb % B_;
    const float* p = pa + ((size_t)b * T_ + t) * N_ * H_;
    __shared__ float piT[64][64];
    __shared__ float pjT[64][64];
    int tid = threadIdx.x;
    int i0 = it * 64, j0 = jt * 64;
#pragma unroll
    for (int q = 0; q < 4; q++) {
        int idx = q * 256 + tid; int hq = idx & 15, i = idx >> 4;
        float4 v = *(const float4*)&p[(size_t)(i0 + i) * 64 + hq * 4];
        piT[hq * 4 + 0][i] = v.x; piT[hq * 4 + 1][i] = v.y; piT[hq * 4 + 2][i] = v.z; piT[hq * 4 + 3][i] = v.w;
        float4 w = *(const float4*)&p[(size_t)(j0 + i) * 64 + hq * 4];
        pjT[hq * 4 + 0][i] = w.x; pjT[hq * 4 + 1][i] = w.y; pjT[hq * 4 + 2][i] = w.z; pjT[hq * 4 + 3][i] = w.w;
    }
    __syncthreads();
    int jg = tid & 15, ig = tid >> 4;
    float acc[4][4];
#pragma unroll
    for (int a = 0; a < 4; a++)
#pragma unroll
        for (int c = 0; c < 4; c++) acc[a][c] = 0.f;
    for (int h = 0; h < 64; h++) {
        float4 a4 = *(const float4*)&piT[h][ig * 4];
        float4 b4 = *(const float4*)&pjT[h][jg * 4];
        float av[4] = { a4.x, a4.y, a4.z, a4.w };
        float bv[4] = { b4.x, b4.y, b4.z, b4.w };
#pragma unroll
        for (int a = 0; a < 4; a++)
#pragma unroll
            for (int c = 0; c < 4; c++) acc[a][c] += fabsf(av[a] - bv[c]);
    }
    float* dst = Ebuf + (size_t)tb * N_ * N_;
#pragma unroll
    for (int a = 0; a < 4; a++) {
        float4 o; o.x = __expf(-acc[a][0]); o.y = __expf(-acc[a][1]);
        o.z = __expf(-acc[a][2]); o.w = __expf(-acc[a][3]);
        *(float4*)&dst[(size_t)(i0 + ig * 4 + a) * N_ + j0 + jg * 4] = o;
    }
}

// ------------- column softmax normalize in-place -------------
__global__ void k_norm(float* NF Ebuf) {
    int tb = blockIdx.x, tid = threadIdx.x;   // 96 x 1024
    int j = tid & 255, q = tid >> 8;
    float* s = Ebuf + (size_t)tb * 65536;
    __shared__ float red[4][256];
    float S = 0.f;
    for (int i = q * 64; i < q * 64 + 64; ++i) S += s[(size_t)i * N_ + j];
    red[q][j] = S; __syncthreads();
    float inv = 1.f / (red[0][j] + red[1][j] + red[2][j] + red[3][j]);
    for (int i = q * 64; i < q * 64 + 64; ++i) s[(size_t)i * N_ + j] *= inv;
}

// ------------- A2[tb] = adj @ E'[tb]  (64x64 out-tiles, 32-m chunks) -------------
__global__ __launch_bounds__(256) void k_a2(const float* NF adjm, const float* NF Ebuf, float* NF A2) {
    int rt = blockIdx.x & 3, ct = blockIdx.x >> 2;   // grid (16, 96)
    int tb = blockIdx.y;
    const float* U = Ebuf + (size_t)tb * N_ * N_;
    int r0 = rt * 64, c0 = ct * 64;
    __shared__ float SL[64][33];
    __shared__ float UL[32][72];
    int tid = threadIdx.x, cg = tid & 15, rg = tid >> 4;
    float acc[4][4];
#pragma unroll
    for (int a = 0; a < 4; a++)
#pragma unroll
        for (int c = 0; c < 4; c++) acc[a][c] = 0.f;
    for (int mc = 0; mc < 8; ++mc) {
        int m0 = mc * 32;
#pragma unroll
        for (int q = 0; q < 2; q++) {
            int idx = q * 256 + tid;
            int r = idx >> 3, mq = idx & 7;
            float4 v = *(const float4*)&adjm[(size_t)(r0 + r) * N_ + m0 + mq * 4];
            SL[r][mq * 4 + 0] = v.x; SL[r][mq * 4 + 1] = v.y;
            SL[r][mq * 4 + 2] = v.z; SL[r][mq * 4 + 3] = v.w;
            int mm = idx >> 4, c4 = idx & 15;
            float4 u = *(const float4*)&U[(size_t)(m0 + mm) * N_ + c0 + c4 * 4];
            *(float4*)&UL[mm][c4 * 4] = u;
        }
        __syncthreads();
        for (int mm = 0; mm < 32; ++mm) {
            float4 uv = *(const float4*)&UL[mm][cg * 4];
            float sv[4];
#pragma unroll
            for (int a = 0; a < 4; a++) sv[a] = SL[rg * 4 + a][mm];
#pragma unroll
            for (int a = 0; a < 4; a++) {
                acc[a][0] = fmaf(sv[a], uv.x, acc[a][0]);
                acc[a][1] = fmaf(sv[a], uv.y, acc[a][1]);
                acc[a][2] = fmaf(sv[a], uv.z, acc[a][2]);
                acc[a][3] = fmaf(sv[a], uv.w, acc[a][3]);
            }
        }
        __syncthreads();
    }
    float* dst = A2 + (size_t)tb * N_ * N_;
#pragma unroll
    for (int a = 0; a < 4; a++) {
        float4 o; o.x = acc[a][0]; o.y = acc[a][1]; o.z = acc[a][2]; o.w = acc[a][3];
        *(float4*)&dst[(size_t)(r0 + rg * 4 + a) * N_ + c0 + cg * 4] = o;
    }
}

// ------------- Y0X = S'_k @ x  (64-row tiles, 4-way m-split + shfl) -------------
__global__ __launch_bounds__(256) void k_y0x(const float* NF Ebuf, const float* NF A2,
                                             const float* NF x, float* NF y0x) {
    int rt = blockIdx.x, tbk = blockIdx.y;   // grid (4, 192)
    int tb = tbk >> 1, kk = tbk & 1;
    int t = tb / B_, b = tb % B_;
    const float* S = (kk ? A2 : Ebuf) + (size_t)tb * N_ * N_;
    const float* xb = x + ((size_t)b * T_ + t) * N_ * 2;
    __shared__ float SL[64][65];
    __shared__ float xw[64][2];
    int tid = threadIdx.x, rg = tid >> 2, mg = tid & 3;
    int r0 = rt * 64;
    float a0 = 0.f, a1 = 0.f;
    for (int mc = 0; mc < 4; ++mc) {
        int m0 = mc * 64;
#pragma unroll
        for (int q = 0; q < 4; q++) {
            int idx = q * 256 + tid; int r = idx >> 4, mq = idx & 15;
            float4 v = *(const float4*)&S[(size_t)(r0 + r) * N_ + m0 + mq * 4];
            SL[r][mq * 4 + 0] = v.x; SL[r][mq * 4 + 1] = v.y;
            SL[r][mq * 4 + 2] = v.z; SL[r][mq * 4 + 3] = v.w;
        }
        if (tid < 128) xw[tid >> 1][tid & 1] = xb[(size_t)(m0 + (tid >> 1)) * 2 + (tid & 1)];
        __syncthreads();
        for (int mm = mg * 16; mm < mg * 16 + 16; ++mm) {
            float s = SL[rg][mm];
            a0 = fmaf(s, xw[mm][0], a0); a1 = fmaf(s, xw[mm][1], a1);
        }
        __syncthreads();
    }
    a0 += __shfl_xor(a0, 1); a0 += __shfl_xor(a0, 2);
    a1 += __shfl_xor(a1, 1); a1 += __shfl_xor(a1, 2);
    if (mg == 0) {
        y0x[(((size_t)tb * 2 + kk) * N_ + r0 + rg) * 2 + 0] = a0;
        y0x[(((size_t)tb * 2 + kk) * N_ + r0 + rg) * 2 + 1] = a1;
    }
}

// ------------- sa init for both layers -------------
__global__ void k_init2(const float* NF ist, const float* NF pa,
                        float* NF u1sa0, float* NF u1sa1) {
    int idx = blockIdx.x * 256 + threadIdx.x;   // 262144
    int l = idx >> 17, r = idx & 131071;
    int b = r >> 14, rem = r & 16383;
    float v = ist[(size_t)l * 131072 + r] + pa[(size_t)b * T_ * 16384 + rem];
    if (l == 0) u1sa0[r] = v; else u1sa1[r] = v;
}

// ========== merged y phase, 2-way m-split (r15/r17 proven body) ==========
__global__ __launch_bounds__(256) void k_py(
    const float* NF Et0, const float* NF A2t0, const float* NF u0,
    const float* NF Et1, const float* NF A2t1, const float* NF cr, long crb,
    const float* NF u1s, float* NF yb0, float* NF yb1, int nb0, int cs_off)
{
    int bid = blockIdx.x, tid = threadIdx.x;
    int layer, rt, g, cs, ms;
    if (bid < 2 * nb0) { layer = 0; ms = bid & 1; int rest = bid >> 1; rt = rest & 3; g = rest >> 2; cs = 0; }
    else { int idx = bid - 2 * nb0; layer = 1; ms = idx & 1; int rest = idx >> 1; rt = rest & 3; g = (rest >> 2) & 15; cs = (rest >> 6) + cs_off; }
    int b = g >> 1, kk = g & 1;
    const float* S = (layer ? (kk ? A2t1 : Et1) : (kk ? A2t0 : Et0)) + (size_t)b * 65536;
    const float* U = layer ? (cs ? (u1s + (size_t)b * 16384) : (cr + (size_t)b * crb))
                           : (u0 + (size_t)b * 16384);
    __shared__ float SL[64][65];
    __shared__ float UL[64][72];
    int r0 = rt * 64;
    int cg = tid & 15, rg = tid >> 4;
    float acc[4][4];
#pragma unroll
    for (int a = 0; a < 4; a++)
#pragma unroll
        for (int c = 0; c < 4; c++) acc[a][c] = 0.f;
    for (int mc = 0; mc < 2; ++mc) {
        int m0 = ms * 128 + mc * 64;
#pragma unroll
        for (int q = 0; q < 4; q++) {
            int idx = q * 256 + tid; int r = idx >> 4, mq = idx & 15;
            float4 v = *(const float4*)&S[(size_t)(r0 + r) * N_ + m0 + mq * 4];
            SL[r][mq * 4 + 0] = v.x; SL[r][mq * 4 + 1] = v.y;
            SL[r][mq * 4 + 2] = v.z; SL[r][mq * 4 + 3] = v.w;
            float4 u = *(const float4*)&U[(size_t)(m0 + r) * 64 + mq * 4];
            *(float4*)&UL[r][mq * 4] = u;
        }
        __syncthreads();
        for (int mm = 0; mm < 64; ++mm) {
            float4 uv = *(const float4*)&UL[mm][cg * 4];
            float sv[4];
#pragma unroll
            for (int a = 0; a < 4; a++) sv[a] = SL[rg * 4 + a][mm];
#pragma unroll
            for (int a = 0; a < 4; a++) {
                acc[a][0] = fmaf(sv[a], uv.x, acc[a][0]);
                acc[a][1] = fmaf(sv[a], uv.y, acc[a][1]);
                acc[a][2] = fmaf(sv[a], uv.z, acc[a][2]);
                acc[a][3] = fmaf(sv[a], uv.w, acc[a][3]);
            }
        }
        __syncthreads();
    }
#pragma unroll
    for (int a = 0; a < 4; a++) {
        float4 o; o.x = acc[a][0]; o.y = acc[a][1]; o.z = acc[a][2]; o.w = acc[a][3];
        if (layer) *(float4*)&yb1[(size_t)ms * 524288 + ((size_t)g * 256 + r0 + rg * 4 + a) * 128 + cs * 64 + cg * 4] = o;
        else       *(float4*)&yb0[(size_t)ms * 262144 + ((size_t)g * 256 + r0 + rg * 4 + a) * 64 + cg * 4] = o;
    }
}

// ========== merged mm phase + GRU epilogues (r15 body, j-loop unroll 8) ==========
template <int MODE>
__global__ __launch_bounds__(256) void k_pm(
    const float* NF yb0, const float* NF yb1, const float* NF Y0Xt,
    const float* NF Wl0, const float* NF Bl0, const float* NF Wl1, const float* NF Bl1,
    float* NF u1sa0, float* NF u2sa0, float* NF rb0,
    float* NF u1sa1, float* NF u2sa1, float* NF rb1,
    const float* NF pa, float* NF cw, long cwb, float* NF seq1,
    float* NF hid0, float* NF hid1, int t0, int t1, int nb0)
{
    constexpr int OT = (MODE == 0) ? 128 : 64;
    int bid = blockIdx.x, tid = threadIdx.x;
    int layer, n, os;
    if (bid < nb0) { layer = 0; n = bid & 255; os = bid >> 8; }
    else { int idx = bid - nb0; layer = 1; n = idx & 255; os = idx >> 8; }
    __shared__ float xg[256][12];
    if (layer == 0) {
        int b = tid >> 5, kk = (tid >> 4) & 1, c = (tid & 15) * 4;
        size_t base = (((size_t)(b * 2 + kk)) * 256 + n) * 64 + c;
        float4 v = *(const float4*)&yb0[base];
        float4 w = *(const float4*)&yb0[base + 262144];
        v.x += w.x; v.y += w.y; v.z += w.z; v.w += w.w;
        int j = kk * 66 + 2 + c;
        xg[j + 0][b] = v.x; xg[j + 1][b] = v.y; xg[j + 2][b] = v.z; xg[j + 3][b] = v.w;
        if (tid < 32) {
            int b2 = tid >> 2, k2 = (tid >> 1) & 1, c2 = tid & 1;
            xg[k2 * 66 + c2][b2] = Y0Xt[(((size_t)(b2 * 2 + k2)) * 256 + n) * 2 + c2];
        }
    } else {
        int b = tid >> 5, kk = (tid >> 4) & 1, cq = tid & 15;
#pragma unroll
        for (int q = 0; q < 2; q++) {
            int c = cq * 4 + q * 64;
            size_t base = (((size_t)(b * 2 + kk)) * 256 + n) * 128 + c;
            float4 v = *(const float4*)&yb1[base];
            float4 w = *(const float4*)&yb1[base + 524288];
            v.x += w.x; v.y += w.y; v.z += w.z; v.w += w.w;
            int j = kk * 128 + c;
            xg[j + 0][b] = v.x; xg[j + 1][b] = v.y; xg[j + 2][b] = v.z; xg[j + 3][b] = v.w;
        }
    }
    __syncthreads();
    int J2 = layer ? 256 : 132;
    const float* W = layer ? Wl1 : Wl0;
    const float* Bb = layer ? Bl1 : Bl0;
    int o_l = tid & 63, bg = tid >> 6;
    int o = os * 64 + o_l;
    float bias = Bb[(size_t)n * OT + o];
    float acc0 = bias, acc1 = bias;
    const float* Wn = W + (size_t)n * J2 * OT + o;
#pragma unroll 8
    for (int j = 0; j < J2; ++j) {
        float w = Wn[(size_t)j * OT];
        float2 xv = *(const float2*)&xg[j][bg * 2];
        acc0 = fmaf(xv.x, w, acc0); acc1 = fmaf(xv.y, w, acc1);
    }
#pragma unroll
    for (int q = 0; q < 2; ++q) {
        int b = bg * 2 + q;
        float a = q ? acc1 : acc0;
        size_t bn = (size_t)b * 256 + n;
        if (MODE == 0) {
            float v = 1.f / (1.f + __expf(-a));
            if (layer == 0) {
                if (o < 64) u2sa0[bn * 64 + o] = v * u1sa0[bn * 64 + o];
                else        rb0[bn * 64 + (o - 64)] = v;
            } else {
                if (o < 64) u2sa1[bn * 64 + o] = v * u1sa1[bn * 64 + o];
                else        rb1[bn * 64 + (o - 64)] = v;
            }
        } else {
            float hc = tanhf(a);
            if (layer == 0) {
                float r = rb0[bn * 64 + o];
                float s = u1sa0[bn * 64 + o];
                float ns = hc + r * (s - hc);
                cw[(size_t)b * cwb + (size_t)n * 64 + o] = ns;
                if (t0 < T_ - 1) u1sa0[bn * 64 + o] = ns + pa[(((size_t)b * T_ + t0 + 1) * 256 + n) * 64 + o];
                else             hid0[bn * 64 + o] = ns;
            } else {
                float r = rb1[bn * 64 + o];
                float s = u1sa1[bn * 64 + o];
                float ns = hc + r * (s - hc);
                seq1[(((size_t)b * T_ + t1) * 256 + n) * 64 + o] = ns;
                if (t1 < T_ - 1) u1sa1[bn * 64 + o] = ns + pa[(((size_t)b * T_ + t1 + 1) * 256 + n) * 64 + o];
                else             hid1[bn * 64 + o] = ns;
            }
        }
    }
}

extern "C" void kernel_launch(void* const* d_in, const int* in_sizes, int n_in,
                              void* d_out, int out_size, void* d_ws, size_t ws_size,
                              hipStream_t stream) {
    const float* x   = (const float*)d_in[0];
    const float* ist = (const float*)d_in[1];
    const float* ne  = (const float*)d_in[2];
    const float* pa  = (const float*)d_in[3];
    const float* gw0 = (const float*)d_in[4];
    const float* gb0 = (const float*)d_in[5];
    const float* uw0 = (const float*)d_in[6];
    const float* ub0 = (const float*)d_in[7];
    const float* gw1 = (const float*)d_in[8];
    const float* gb1 = (const float*)d_in[9];
    const float* uw1 = (const float*)d_in[10];
    const float* ub1 = (const float*)d_in[11];
    float* out = (float*)d_out;
    char*  base = (char*)d_ws;

    float* cur_out = out;                                   // (B,T,N,H)
    float* hid_out = out + (size_t)B_ * T_ * N_ * H_;       // (2,B,N,H)
    float* hid0 = hid_out, * hid1 = hid_out + 131072;

    size_t off = 0;
    auto carve = [&](size_t bytes) { char* p = base + off; off += (bytes + 255) & ~(size_t)255; return p; };
    float* adjw  = (float*)carve(65536ull * 4);
    float* Ebuf  = (float*)carve(6291456ull * 4);
    float* A2    = (float*)carve(6291456ull * 4);
    float* Bg0   = (float*)carve(32768ull * 4);
    float* Bu0   = (float*)carve(16384ull * 4);
    float* Bg1   = (float*)carve(32768ull * 4);
    float* Bu1   = (float*)carve(16384ull * 4);
    float* u1sa0 = (float*)carve(131072ull * 4);
    float* u2sa0 = (float*)carve(131072ull * 4);
    float* rb0   = (float*)carve(131072ull * 4);
    float* u1sa1 = (float*)carve(131072ull * 4);
    float* u2sa1 = (float*)carve(131072ull * 4);
    float* rb1   = (float*)carve(131072ull * 4);
    float* cbuf  = (float*)carve(131072ull * 4);
    float* yb0   = (float*)carve(524288ull * 4);    // 2 m-split slots
    float* yb1   = (float*)carve(1048576ull * 4);   // 2 m-split slots
    float* y0x   = hid1;   // alias: y0x lives in hid1 region until final phase
    size_t common_end = off;
    float* Wg0 = (float*)carve(4325376ull * 4);
    float* Wu0 = (float*)carve(2162688ull * 4);
    float* Wg1 = (float*)carve(8388608ull * 4);
    float* Wu1 = (float*)carve(4194304ull * 4);
    bool pipe = (off <= ws_size);
    if (!pipe) {
        off = common_end;
        float* WgS = (float*)carve(8388608ull * 4);
        float* WuS = (float*)carve(4194304ull * 4);
        if (off > ws_size) { k_sentinel<<<1, 1, 0, stream>>>(out); return; }
        Wg0 = Wg1 = WgS; Wu0 = Wu1 = WuS;
    }

    // ---- time-invariant precompute ----
    k_adj<<<256, 256, 0, stream>>>(ne, adjw);
    k_sub_t<<<dim3(16, 96), 256, 0, stream>>>(pa, Ebuf);
    k_norm<<<96, 1024, 0, stream>>>(Ebuf);
    k_a2<<<dim3(16, 96), 256, 0, stream>>>(adjw, Ebuf, A2);
    k_y0x<<<dim3(4, 192), 256, 0, stream>>>(Ebuf, A2, x, y0x);
    k_bias4<<<256, 192, 0, stream>>>(ne, gb0, ub0, gb1, ub1, Bg0, Bu0, Bg1, Bu1);
    k_init2<<<1024, 256, 0, stream>>>(ist, pa, u1sa0, u1sa1);

    // one super-step: l0 at t0 (if a0), l1 at t1 (if a1)
    auto super = [&](int t0, int t1, bool a0, bool a1, float* cw, long cwb,
                     const float* cr, long crb) {
        const float* Et0  = Ebuf + (size_t)t0 * B_ * 65536;
        const float* A2t0 = A2   + (size_t)t0 * B_ * 65536;
        const float* Et1  = Ebuf + (size_t)t1 * B_ * 65536;
        const float* A2t1 = A2   + (size_t)t1 * B_ * 65536;
        const float* YXt  = y0x  + (size_t)t0 * B_ * 2 * N_ * 2;
        int y0n = a0 ? 64 : 0;
        int m0g = a0 ? 512 : 0, m0u = a0 ? 256 : 0;
        k_py<<<2 * y0n + (a1 ? 256 : 0), 256, 0, stream>>>(Et0, A2t0, u1sa0, Et1, A2t1, cr, crb, u1sa1, yb0, yb1, y0n, 0);
        k_pm<0><<<m0g + (a1 ? 512 : 0), 256, 0, stream>>>(yb0, yb1, YXt, Wg0, Bg0, Wg1, Bg1,
            u1sa0, u2sa0, rb0, u1sa1, u2sa1, rb1, pa, cw, cwb, cur_out, hid0, hid1, t0, t1, m0g);
        k_py<<<2 * y0n + (a1 ? 128 : 0), 256, 0, stream>>>(Et0, A2t0, u2sa0, Et1, A2t1, cr, crb, u2sa1, yb0, yb1, y0n, 1);
        k_pm<1><<<m0u + (a1 ? 256 : 0), 256, 0, stream>>>(yb0, yb1, YXt, Wu0, Bu0, Wu1, Bu1,
            u1sa0, u2sa0, rb0, u1sa1, u2sa1, rb1, pa, cw, cwb, cur_out, hid0, hid1, t0, t1, m0u);
    };

    if (pipe) {
        k_wpool4<<<4656, 256, 0, stream>>>(ne, gw0, uw0, gw1, uw1, Wg0, Wu0, Wg1, Wu1);
        for (int s = 0; s <= 12; ++s) {
            bool a0 = (s < 12), a1 = (s >= 1);
            int t0 = a0 ? s : 11, t1 = a1 ? s - 1 : 0;
            super(t0, t1, a0, a1, cbuf, 16384L, cbuf, 16384L);
        }
    } else {
        {
            int t4g = N_ * 132 * 128 / 4, t4u = N_ * 132 * 64 / 4;
            k_wpool<<<(t4g + 255) / 256, 256, 0, stream>>>(ne, gw0, Wg0, 132, 32, t4g);
            k_wpool<<<(t4u + 255) / 256, 256, 0, stream>>>(ne, uw0, Wu0, 132, 16, t4u);
        }
        for (int t = 0; t < T_; ++t)
            super(t, 0, true, false, cur_out + (size_t)t * 16384, (long)T_ * 16384, cbuf, 16384L);
        {
            int t4g = N_ * 256 * 128 / 4, t4u = N_ * 256 * 64 / 4;
            k_wpool<<<(t4g + 255) / 256, 256, 0, stream>>>(ne, gw1, Wg1, 256, 32, t4g);
            k_wpool<<<(t4u + 255) / 256, 256, 0, stream>>>(ne, uw1, Wu1, 256, 16, t4u);
        }
        for (int t = 0; t < T_; ++t)
            super(0, t, false, true, cbuf, 16384L, cur_out + (size_t)t * 16384, (long)T_ * 16384);
    }
    (void)in_sizes; (void)n_in; (void)out_size;
}

// Round 19
// 705.935 us; speedup vs baseline: 3.3982x; 1.1093x over previous
//
#include <hip/hip_runtime.h>
#include <math.h>

// AVWDCRNN round 19 (all-f32). r18=783us (unroll 4->8 on k_pm: -194us,
// steady mm proven latency-bound). Same lever deeper:
//  - k_pm j-loop unroll 8 -> 16 (VGPR ~90, no spill expected).
//  - k_a2 inner mm loop unroll 8 (one-time 52us kernel, same logic).
// Serial accumulator chains -> bit-identical output.

#define NF __restrict__
constexpr int N_ = 256, B_ = 8, T_ = 12, H_ = 64, E_ = 16;

__global__ void k_sentinel(float* NF out) { out[0] = 1.0e6f; }

// ---------------- adj = softmax(relu(ne ne^T), axis=1) ----------------
__global__ void k_adj(const float* NF ne, float* NF adj) {
    int n = blockIdx.x, m = threadIdx.x;
    __shared__ float en[E_];
    __shared__ float red[256];
    if (m < E_) en[m] = ne[n * E_ + m];
    __syncthreads();
    float s = 0.f;
#pragma unroll
    for (int d = 0; d < E_; d++) s += en[d] * ne[m * E_ + d];
    s = fmaxf(s, 0.f);
    red[m] = s; __syncthreads();
    for (int st = 128; st > 0; st >>= 1) { if (m < st) red[m] = fmaxf(red[m], red[m + st]); __syncthreads(); }
    float mx = red[0]; __syncthreads();
    float e = __expf(s - mx);
    red[m] = e; __syncthreads();
    for (int st = 128; st > 0; st >>= 1) { if (m < st) red[m] += red[m + st]; __syncthreads(); }
    adj[(size_t)n * N_ + m] = e / red[0];
}

// ------------- all four biases in one launch -------------
__global__ void k_bias4(const float* NF ne, const float* NF gb0, const float* NF ub0,
                        const float* NF gb1, const float* NF ub1,
                        float* NF Bg0, float* NF Bu0, float* NF Bg1, float* NF Bu1) {
    int n = blockIdx.x, tid = threadIdx.x;
    __shared__ float e[E_];
    if (tid < E_) e[tid] = ne[n * E_ + tid];
    __syncthreads();
    if (tid < 128) {
        float a0 = 0.f, a1 = 0.f;
#pragma unroll
        for (int d = 0; d < E_; d++) { a0 = fmaf(e[d], gb0[d * 128 + tid], a0); a1 = fmaf(e[d], gb1[d * 128 + tid], a1); }
        Bg0[(size_t)n * 128 + tid] = a0; Bg1[(size_t)n * 128 + tid] = a1;
    } else {
        int o = tid - 128;
        float a0 = 0.f, a1 = 0.f;
#pragma unroll
        for (int d = 0; d < E_; d++) { a0 = fmaf(e[d], ub0[d * 64 + o], a0); a1 = fmaf(e[d], ub1[d * 64 + o], a1); }
        Bu0[(size_t)n * 64 + o] = a0; Bu1[(size_t)n * 64 + o] = a1;
    }
}

// ------------- single-buffer W pool (fallback tier) -------------
__global__ void k_wpool(const float* NF ne, const float* NF wp, float* NF W,
                        int I2, int O4, int total4) {
    int idx4 = blockIdx.x * 256 + threadIdx.x;
    if (idx4 >= total4) return;
    int o4 = idx4 % O4; int rem = idx4 / O4; int j = rem % I2; int n = rem / I2;
    const float* nrow = ne + n * E_;
    float ax = 0.f, ay = 0.f, az = 0.f, aw = 0.f;
#pragma unroll
    for (int d = 0; d < E_; d++) {
        float e = nrow[d];
        const float4 w = *(const float4*)&wp[(((size_t)d * I2 + j) * O4 + o4) * 4];
        ax = fmaf(e, w.x, ax); ay = fmaf(e, w.y, ay); az = fmaf(e, w.z, az); aw = fmaf(e, w.w, aw);
    }
    float4 r; r.x = ax; r.y = ay; r.z = az; r.w = aw;
    *(float4*)&W[(size_t)idx4 * 4] = r;
}

// ------------- all 4 W pools: reuse-blocked (64 col4 x 16 nodes/block) -------------
__global__ __launch_bounds__(256) void k_wpool4(const float* NF ne,
                         const float* NF gw0, const float* NF uw0,
                         const float* NF gw1, const float* NF uw1,
                         float* NF Wg0, float* NF Wu0, float* NF Wg1, float* NF Wu1) {
    int cb = blockIdx.x % 291, nb = blockIdx.x / 291;
    const float* wp; float* W; int O4, c0;
    if (cb < 66)       { wp = gw0; W = Wg0; O4 = 4224; c0 = cb * 64; }
    else if (cb < 99)  { wp = uw0; W = Wu0; O4 = 2112; c0 = (cb - 66) * 64; }
    else if (cb < 227) { wp = gw1; W = Wg1; O4 = 8192; c0 = (cb - 99) * 64; }
    else               { wp = uw1; W = Wu1; O4 = 4096; c0 = (cb - 227) * 64; }
    __shared__ float4 PL[16][64];
    __shared__ float  eL[16][17];
    int tid = threadIdx.x;
#pragma unroll
    for (int q = 0; q < 4; q++) {
        int idx = q * 256 + tid; int d = idx >> 6, c = idx & 63;
        PL[d][c] = *(const float4*)&wp[((size_t)d * O4 + c0 + c) * 4];
    }
    int n0 = nb * 16;
    { int nn = tid >> 4, d = tid & 15; eL[nn][d] = ne[(n0 + nn) * E_ + d]; }
    __syncthreads();
    int c = tid & 63, ng = tid >> 6;
#pragma unroll
    for (int q = 0; q < 4; q++) {
        int nn = ng * 4 + q;
        float ax = 0.f, ay = 0.f, az = 0.f, aw = 0.f;
#pragma unroll
        for (int d = 0; d < E_; d++) {
            float e = eL[nn][d];
            float4 w = PL[d][c];
            ax = fmaf(e, w.x, ax); ay = fmaf(e, w.y, ay);
            az = fmaf(e, w.z, az); aw = fmaf(e, w.w, aw);
        }
        float4 r; r.x = ax; r.y = ay; r.z = az; r.w = aw;
        *(float4*)&W[((size_t)(n0 + nn) * O4 + c0 + c) * 4] = r;
    }
}

// ------------- E[tb,i,j] = exp(-L1(pa_i, pa_j)) ; tiled 64x64 -------------
__global__ __launch_bounds__(256) void k_sub_t(const float* NF pa, float* NF Ebuf) {
    int bx = blockIdx.x, tb = blockIdx.y;    // grid (16, 96)
    int it = bx & 3, jt = bx >> 2;
    int t = tb / B_, b = tb % B_;
    const float* p = pa + ((size_t)b * T_ + t) * N_ * H_;
    __shared__ float piT[64][64];
    __shared__ float pjT[64][64];
    int tid = threadIdx.x;
    int i0 = it * 64, j0 = jt * 64;
#pragma unroll
    for (int q = 0; q < 4; q++) {
        int idx = q * 256 + tid; int hq = idx & 15, i = idx >> 4;
        float4 v = *(const float4*)&p[(size_t)(i0 + i) * 64 + hq * 4];
        piT[hq * 4 + 0][i] = v.x; piT[hq * 4 + 1][i] = v.y; piT[hq * 4 + 2][i] = v.z; piT[hq * 4 + 3][i] = v.w;
        float4 w = *(const float4*)&p[(size_t)(j0 + i) * 64 + hq * 4];
        pjT[hq * 4 + 0][i] = w.x; pjT[hq * 4 + 1][i] = w.y; pjT[hq * 4 + 2][i] = w.z; pjT[hq * 4 + 3][i] = w.w;
    }
    __syncthreads();
    int jg = tid & 15, ig = tid >> 4;
    float acc[4][4];
#pragma unroll
    for (int a = 0; a < 4; a++)
#pragma unroll
        for (int c = 0; c < 4; c++) acc[a][c] = 0.f;
    for (int h = 0; h < 64; h++) {
        float4 a4 = *(const float4*)&piT[h][ig * 4];
        float4 b4 = *(const float4*)&pjT[h][jg * 4];
        float av[4] = { a4.x, a4.y, a4.z, a4.w };
        float bv[4] = { b4.x, b4.y, b4.z, b4.w };
#pragma unroll
        for (int a = 0; a < 4; a++)
#pragma unroll
            for (int c = 0; c < 4; c++) acc[a][c] += fabsf(av[a] - bv[c]);
    }
    float* dst = Ebuf + (size_t)tb * N_ * N_;
#pragma unroll
    for (int a = 0; a < 4; a++) {
        float4 o; o.x = __expf(-acc[a][0]); o.y = __expf(-acc[a][1]);
        o.z = __expf(-acc[a][2]); o.w = __expf(-acc[a][3]);
        *(float4*)&dst[(size_t)(i0 + ig * 4 + a) * N_ + j0 + jg * 4] = o;
    }
}

// ------------- column softmax normalize in-place -------------
__global__ void k_norm(float* NF Ebuf) {
    int tb = blockIdx.x, tid = threadIdx.x;   // 96 x 1024
    int j = tid & 255, q = tid >> 8;
    float* s = Ebuf + (size_t)tb * 65536;
    __shared__ float red[4][256];
    float S = 0.f;
    for (int i = q * 64; i < q * 64 + 64; ++i) S += s[(size_t)i * N_ + j];
    red[q][j] = S; __syncthreads();
    float inv = 1.f / (red[0][j] + red[1][j] + red[2][j] + red[3][j]);
    for (int i = q * 64; i < q * 64 + 64; ++i) s[(size_t)i * N_ + j] *= inv;
}

// ------------- A2[tb] = adj @ E'[tb]  (64x64 out-tiles, 32-m chunks, unroll 8) -------------
__global__ __launch_bounds__(256) void k_a2(const float* NF adjm, const float* NF Ebuf, float* NF A2) {
    int rt = blockIdx.x & 3, ct = blockIdx.x >> 2;   // grid (16, 96)
    int tb = blockIdx.y;
    const float* U = Ebuf + (size_t)tb * N_ * N_;
    int r0 = rt * 64, c0 = ct * 64;
    __shared__ float SL[64][33];
    __shared__ float UL[32][72];
    int tid = threadIdx.x, cg = tid & 15, rg = tid >> 4;
    float acc[4][4];
#pragma unroll
    for (int a = 0; a < 4; a++)
#pragma unroll
        for (int c = 0; c < 4; c++) acc[a][c] = 0.f;
    for (int mc = 0; mc < 8; ++mc) {
        int m0 = mc * 32;
#pragma unroll
        for (int q = 0; q < 2; q++) {
            int idx = q * 256 + tid;
            int r = idx >> 3, mq = idx & 7;
            float4 v = *(const float4*)&adjm[(size_t)(r0 + r) * N_ + m0 + mq * 4];
            SL[r][mq * 4 + 0] = v.x; SL[r][mq * 4 + 1] = v.y;
            SL[r][mq * 4 + 2] = v.z; SL[r][mq * 4 + 3] = v.w;
            int mm = idx >> 4, c4 = idx & 15;
            float4 u = *(const float4*)&U[(size_t)(m0 + mm) * N_ + c0 + c4 * 4];
            *(float4*)&UL[mm][c4 * 4] = u;
        }
        __syncthreads();
#pragma unroll 8
        for (int mm = 0; mm < 32; ++mm) {
            float4 uv = *(const float4*)&UL[mm][cg * 4];
            float sv[4];
#pragma unroll
            for (int a = 0; a < 4; a++) sv[a] = SL[rg * 4 + a][mm];
#pragma unroll
            for (int a = 0; a < 4; a++) {
                acc[a][0] = fmaf(sv[a], uv.x, acc[a][0]);
                acc[a][1] = fmaf(sv[a], uv.y, acc[a][1]);
                acc[a][2] = fmaf(sv[a], uv.z, acc[a][2]);
                acc[a][3] = fmaf(sv[a], uv.w, acc[a][3]);
            }
        }
        __syncthreads();
    }
    float* dst = A2 + (size_t)tb * N_ * N_;
#pragma unroll
    for (int a = 0; a < 4; a++) {
        float4 o; o.x = acc[a][0]; o.y = acc[a][1]; o.z = acc[a][2]; o.w = acc[a][3];
        *(float4*)&dst[(size_t)(r0 + rg * 4 + a) * N_ + c0 + cg * 4] = o;
    }
}

// ------------- Y0X = S'_k @ x  (64-row tiles, 4-way m-split + shfl) -------------
__global__ __launch_bounds__(256) void k_y0x(const float* NF Ebuf, const float* NF A2,
                                             const float* NF x, float* NF y0x) {
    int rt = blockIdx.x, tbk = blockIdx.y;   // grid (4, 192)
    int tb = tbk >> 1, kk = tbk & 1;
    int t = tb / B_, b = tb % B_;
    const float* S = (kk ? A2 : Ebuf) + (size_t)tb * N_ * N_;
    const float* xb = x + ((size_t)b * T_ + t) * N_ * 2;
    __shared__ float SL[64][65];
    __shared__ float xw[64][2];
    int tid = threadIdx.x, rg = tid >> 2, mg = tid & 3;
    int r0 = rt * 64;
    float a0 = 0.f, a1 = 0.f;
    for (int mc = 0; mc < 4; ++mc) {
        int m0 = mc * 64;
#pragma unroll
        for (int q = 0; q < 4; q++) {
            int idx = q * 256 + tid; int r = idx >> 4, mq = idx & 15;
            float4 v = *(const float4*)&S[(size_t)(r0 + r) * N_ + m0 + mq * 4];
            SL[r][mq * 4 + 0] = v.x; SL[r][mq * 4 + 1] = v.y;
            SL[r][mq * 4 + 2] = v.z; SL[r][mq * 4 + 3] = v.w;
        }
        if (tid < 128) xw[tid >> 1][tid & 1] = xb[(size_t)(m0 + (tid >> 1)) * 2 + (tid & 1)];
        __syncthreads();
        for (int mm = mg * 16; mm < mg * 16 + 16; ++mm) {
            float s = SL[rg][mm];
            a0 = fmaf(s, xw[mm][0], a0); a1 = fmaf(s, xw[mm][1], a1);
        }
        __syncthreads();
    }
    a0 += __shfl_xor(a0, 1); a0 += __shfl_xor(a0, 2);
    a1 += __shfl_xor(a1, 1); a1 += __shfl_xor(a1, 2);
    if (mg == 0) {
        y0x[(((size_t)tb * 2 + kk) * N_ + r0 + rg) * 2 + 0] = a0;
        y0x[(((size_t)tb * 2 + kk) * N_ + r0 + rg) * 2 + 1] = a1;
    }
}

// ------------- sa init for both layers -------------
__global__ void k_init2(const float* NF ist, const float* NF pa,
                        float* NF u1sa0, float* NF u1sa1) {
    int idx = blockIdx.x * 256 + threadIdx.x;   // 262144
    int l = idx >> 17, r = idx & 131071;
    int b = r >> 14, rem = r & 16383;
    float v = ist[(size_t)l * 131072 + r] + pa[(size_t)b * T_ * 16384 + rem];
    if (l == 0) u1sa0[r] = v; else u1sa1[r] = v;
}

// ========== merged y phase, 2-way m-split (r15/r17 proven body) ==========
__global__ __launch_bounds__(256) void k_py(
    const float* NF Et0, const float* NF A2t0, const float* NF u0,
    const float* NF Et1, const float* NF A2t1, const float* NF cr, long crb,
    const float* NF u1s, float* NF yb0, float* NF yb1, int nb0, int cs_off)
{
    int bid = blockIdx.x, tid = threadIdx.x;
    int layer, rt, g, cs, ms;
    if (bid < 2 * nb0) { layer = 0; ms = bid & 1; int rest = bid >> 1; rt = rest & 3; g = rest >> 2; cs = 0; }
    else { int idx = bid - 2 * nb0; layer = 1; ms = idx & 1; int rest = idx >> 1; rt = rest & 3; g = (rest >> 2) & 15; cs = (rest >> 6) + cs_off; }
    int b = g >> 1, kk = g & 1;
    const float* S = (layer ? (kk ? A2t1 : Et1) : (kk ? A2t0 : Et0)) + (size_t)b * 65536;
    const float* U = layer ? (cs ? (u1s + (size_t)b * 16384) : (cr + (size_t)b * crb))
                           : (u0 + (size_t)b * 16384);
    __shared__ float SL[64][65];
    __shared__ float UL[64][72];
    int r0 = rt * 64;
    int cg = tid & 15, rg = tid >> 4;
    float acc[4][4];
#pragma unroll
    for (int a = 0; a < 4; a++)
#pragma unroll
        for (int c = 0; c < 4; c++) acc[a][c] = 0.f;
    for (int mc = 0; mc < 2; ++mc) {
        int m0 = ms * 128 + mc * 64;
#pragma unroll
        for (int q = 0; q < 4; q++) {
            int idx = q * 256 + tid; int r = idx >> 4, mq = idx & 15;
            float4 v = *(const float4*)&S[(size_t)(r0 + r) * N_ + m0 + mq * 4];
            SL[r][mq * 4 + 0] = v.x; SL[r][mq * 4 + 1] = v.y;
            SL[r][mq * 4 + 2] = v.z; SL[r][mq * 4 + 3] = v.w;
            float4 u = *(const float4*)&U[(size_t)(m0 + r) * 64 + mq * 4];
            *(float4*)&UL[r][mq * 4] = u;
        }
        __syncthreads();
        for (int mm = 0; mm < 64; ++mm) {
            float4 uv = *(const float4*)&UL[mm][cg * 4];
            float sv[4];
#pragma unroll
            for (int a = 0; a < 4; a++) sv[a] = SL[rg * 4 + a][mm];
#pragma unroll
            for (int a = 0; a < 4; a++) {
                acc[a][0] = fmaf(sv[a], uv.x, acc[a][0]);
                acc[a][1] = fmaf(sv[a], uv.y, acc[a][1]);
                acc[a][2] = fmaf(sv[a], uv.z, acc[a][2]);
                acc[a][3] = fmaf(sv[a], uv.w, acc[a][3]);
            }
        }
        __syncthreads();
    }
#pragma unroll
    for (int a = 0; a < 4; a++) {
        float4 o; o.x = acc[a][0]; o.y = acc[a][1]; o.z = acc[a][2]; o.w = acc[a][3];
        if (layer) *(float4*)&yb1[(size_t)ms * 524288 + ((size_t)g * 256 + r0 + rg * 4 + a) * 128 + cs * 64 + cg * 4] = o;
        else       *(float4*)&yb0[(size_t)ms * 262144 + ((size_t)g * 256 + r0 + rg * 4 + a) * 64 + cg * 4] = o;
    }
}

// ========== merged mm phase + GRU epilogues (j-loop unroll 16) ==========
template <int MODE>
__global__ __launch_bounds__(256) void k_pm(
    const float* NF yb0, const float* NF yb1, const float* NF Y0Xt,
    const float* NF Wl0, const float* NF Bl0, const float* NF Wl1, const float* NF Bl1,
    float* NF u1sa0, float* NF u2sa0, float* NF rb0,
    float* NF u1sa1, float* NF u2sa1, float* NF rb1,
    const float* NF pa, float* NF cw, long cwb, float* NF seq1,
    float* NF hid0, float* NF hid1, int t0, int t1, int nb0)
{
    constexpr int OT = (MODE == 0) ? 128 : 64;
    int bid = blockIdx.x, tid = threadIdx.x;
    int layer, n, os;
    if (bid < nb0) { layer = 0; n = bid & 255; os = bid >> 8; }
    else { int idx = bid - nb0; layer = 1; n = idx & 255; os = idx >> 8; }
    __shared__ float xg[256][12];
    if (layer == 0) {
        int b = tid >> 5, kk = (tid >> 4) & 1, c = (tid & 15) * 4;
        size_t base = (((size_t)(b * 2 + kk)) * 256 + n) * 64 + c;
        float4 v = *(const float4*)&yb0[base];
        float4 w = *(const float4*)&yb0[base + 262144];
        v.x += w.x; v.y += w.y; v.z += w.z; v.w += w.w;
        int j = kk * 66 + 2 + c;
        xg[j + 0][b] = v.x; xg[j + 1][b] = v.y; xg[j + 2][b] = v.z; xg[j + 3][b] = v.w;
        if (tid < 32) {
            int b2 = tid >> 2, k2 = (tid >> 1) & 1, c2 = tid & 1;
            xg[k2 * 66 + c2][b2] = Y0Xt[(((size_t)(b2 * 2 + k2)) * 256 + n) * 2 + c2];
        }
    } else {
        int b = tid >> 5, kk = (tid >> 4) & 1, cq = tid & 15;
#pragma unroll
        for (int q = 0; q < 2; q++) {
            int c = cq * 4 + q * 64;
            size_t base = (((size_t)(b * 2 + kk)) * 256 + n) * 128 + c;
            float4 v = *(const float4*)&yb1[base];
            float4 w = *(const float4*)&yb1[base + 524288];
            v.x += w.x; v.y += w.y; v.z += w.z; v.w += w.w;
            int j = kk * 128 + c;
            xg[j + 0][b] = v.x; xg[j + 1][b] = v.y; xg[j + 2][b] = v.z; xg[j + 3][b] = v.w;
        }
    }
    __syncthreads();
    int J2 = layer ? 256 : 132;
    const float* W = layer ? Wl1 : Wl0;
    const float* Bb = layer ? Bl1 : Bl0;
    int o_l = tid & 63, bg = tid >> 6;
    int o = os * 64 + o_l;
    float bias = Bb[(size_t)n * OT + o];
    float acc0 = bias, acc1 = bias;
    const float* Wn = W + (size_t)n * J2 * OT + o;
#pragma unroll 16
    for (int j = 0; j < J2; ++j) {
        float w = Wn[(size_t)j * OT];
        float2 xv = *(const float2*)&xg[j][bg * 2];
        acc0 = fmaf(xv.x, w, acc0); acc1 = fmaf(xv.y, w, acc1);
    }
#pragma unroll
    for (int q = 0; q < 2; ++q) {
        int b = bg * 2 + q;
        float a = q ? acc1 : acc0;
        size_t bn = (size_t)b * 256 + n;
        if (MODE == 0) {
            float v = 1.f / (1.f + __expf(-a));
            if (layer == 0) {
                if (o < 64) u2sa0[bn * 64 + o] = v * u1sa0[bn * 64 + o];
                else        rb0[bn * 64 + (o - 64)] = v;
            } else {
                if (o < 64) u2sa1[bn * 64 + o] = v * u1sa1[bn * 64 + o];
                else        rb1[bn * 64 + (o - 64)] = v;
            }
        } else {
            float hc = tanhf(a);
            if (layer == 0) {
                float r = rb0[bn * 64 + o];
                float s = u1sa0[bn * 64 + o];
                float ns = hc + r * (s - hc);
                cw[(size_t)b * cwb + (size_t)n * 64 + o] = ns;
                if (t0 < T_ - 1) u1sa0[bn * 64 + o] = ns + pa[(((size_t)b * T_ + t0 + 1) * 256 + n) * 64 + o];
                else             hid0[bn * 64 + o] = ns;
            } else {
                float r = rb1[bn * 64 + o];
                float s = u1sa1[bn * 64 + o];
                float ns = hc + r * (s - hc);
                seq1[(((size_t)b * T_ + t1) * 256 + n) * 64 + o] = ns;
                if (t1 < T_ - 1) u1sa1[bn * 64 + o] = ns + pa[(((size_t)b * T_ + t1 + 1) * 256 + n) * 64 + o];
                else             hid1[bn * 64 + o] = ns;
            }
        }
    }
}

extern "C" void kernel_launch(void* const* d_in, const int* in_sizes, int n_in,
                              void* d_out, int out_size, void* d_ws, size_t ws_size,
                              hipStream_t stream) {
    const float* x   = (const float*)d_in[0];
    const float* ist = (const float*)d_in[1];
    const float* ne  = (const float*)d_in[2];
    const float* pa  = (const float*)d_in[3];
    const float* gw0 = (const float*)d_in[4];
    const float* gb0 = (const float*)d_in[5];
    const float* uw0 = (const float*)d_in[6];
    const float* ub0 = (const float*)d_in[7];
    const float* gw1 = (const float*)d_in[8];
    const float* gb1 = (const float*)d_in[9];
    const float* uw1 = (const float*)d_in[10];
    const float* ub1 = (const float*)d_in[11];
    float* out = (float*)d_out;
    char*  base = (char*)d_ws;

    float* cur_out = out;                                   // (B,T,N,H)
    float* hid_out = out + (size_t)B_ * T_ * N_ * H_;       // (2,B,N,H)
    float* hid0 = hid_out, * hid1 = hid_out + 131072;

    size_t off = 0;
    auto carve = [&](size_t bytes) { char* p = base + off; off += (bytes + 255) & ~(size_t)255; return p; };
    float* adjw  = (float*)carve(65536ull * 4);
    float* Ebuf  = (float*)carve(6291456ull * 4);
    float* A2    = (float*)carve(6291456ull * 4);
    float* Bg0   = (float*)carve(32768ull * 4);
    float* Bu0   = (float*)carve(16384ull * 4);
    float* Bg1   = (float*)carve(32768ull * 4);
    float* Bu1   = (float*)carve(16384ull * 4);
    float* u1sa0 = (float*)carve(131072ull * 4);
    float* u2sa0 = (float*)carve(131072ull * 4);
    float* rb0   = (float*)carve(131072ull * 4);
    float* u1sa1 = (float*)carve(131072ull * 4);
    float* u2sa1 = (float*)carve(131072ull * 4);
    float* rb1   = (float*)carve(131072ull * 4);
    float* cbuf  = (float*)carve(131072ull * 4);
    float* yb0   = (float*)carve(524288ull * 4);    // 2 m-split slots
    float* yb1   = (float*)carve(1048576ull * 4);   // 2 m-split slots
    float* y0x   = hid1;   // alias: y0x lives in hid1 region until final phase
    size_t common_end = off;
    float* Wg0 = (float*)carve(4325376ull * 4);
    float* Wu0 = (float*)carve(2162688ull * 4);
    float* Wg1 = (float*)carve(8388608ull * 4);
    float* Wu1 = (float*)carve(4194304ull * 4);
    bool pipe = (off <= ws_size);
    if (!pipe) {
        off = common_end;
        float* WgS = (float*)carve(8388608ull * 4);
        float* WuS = (float*)carve(4194304ull * 4);
        if (off > ws_size) { k_sentinel<<<1, 1, 0, stream>>>(out); return; }
        Wg0 = Wg1 = WgS; Wu0 = Wu1 = WuS;
    }

    // ---- time-invariant precompute ----
    k_adj<<<256, 256, 0, stream>>>(ne, adjw);
    k_sub_t<<<dim3(16, 96), 256, 0, stream>>>(pa, Ebuf);
    k_norm<<<96, 1024, 0, stream>>>(Ebuf);
    k_a2<<<dim3(16, 96), 256, 0, stream>>>(adjw, Ebuf, A2);
    k_y0x<<<dim3(4, 192), 256, 0, stream>>>(Ebuf, A2, x, y0x);
    k_bias4<<<256, 192, 0, stream>>>(ne, gb0, ub0, gb1, ub1, Bg0, Bu0, Bg1, Bu1);
    k_init2<<<1024, 256, 0, stream>>>(ist, pa, u1sa0, u1sa1);

    // one super-step: l0 at t0 (if a0), l1 at t1 (if a1)
    auto super = [&](int t0, int t1, bool a0, bool a1, float* cw, long cwb,
                     const float* cr, long crb) {
        const float* Et0  = Ebuf + (size_t)t0 * B_ * 65536;
        const float* A2t0 = A2   + (size_t)t0 * B_ * 65536;
        const float* Et1  = Ebuf + (size_t)t1 * B_ * 65536;
        const float* A2t1 = A2   + (size_t)t1 * B_ * 65536;
        const float* YXt  = y0x  + (size_t)t0 * B_ * 2 * N_ * 2;
        int y0n = a0 ? 64 : 0;
        int m0g = a0 ? 512 : 0, m0u = a0 ? 256 : 0;
        k_py<<<2 * y0n + (a1 ? 256 : 0), 256, 0, stream>>>(Et0, A2t0, u1sa0, Et1, A2t1, cr, crb, u1sa1, yb0, yb1, y0n, 0);
        k_pm<0><<<m0g + (a1 ? 512 : 0), 256, 0, stream>>>(yb0, yb1, YXt, Wg0, Bg0, Wg1, Bg1,
            u1sa0, u2sa0, rb0, u1sa1, u2sa1, rb1, pa, cw, cwb, cur_out, hid0, hid1, t0, t1, m0g);
        k_py<<<2 * y0n + (a1 ? 128 : 0), 256, 0, stream>>>(Et0, A2t0, u2sa0, Et1, A2t1, cr, crb, u2sa1, yb0, yb1, y0n, 1);
        k_pm<1><<<m0u + (a1 ? 256 : 0), 256, 0, stream>>>(yb0, yb1, YXt, Wu0, Bu0, Wu1, Bu1,
            u1sa0, u2sa0, rb0, u1sa1, u2sa1, rb1, pa, cw, cwb, cur_out, hid0, hid1, t0, t1, m0u);
    };

    if (pipe) {
        k_wpool4<<<4656, 256, 0, stream>>>(ne, gw0, uw0, gw1, uw1, Wg0, Wu0, Wg1, Wu1);
        for (int s = 0; s <= 12; ++s) {
            bool a0 = (s < 12), a1 = (s >= 1);
            int t0 = a0 ? s : 11, t1 = a1 ? s - 1 : 0;
            super(t0, t1, a0, a1, cbuf, 16384L, cbuf, 16384L);
        }
    } else {
        {
            int t4g = N_ * 132 * 128 / 4, t4u = N_ * 132 * 64 / 4;
            k_wpool<<<(t4g + 255) / 256, 256, 0, stream>>>(ne, gw0, Wg0, 132, 32, t4g);
            k_wpool<<<(t4u + 255) / 256, 256, 0, stream>>>(ne, uw0, Wu0, 132, 16, t4u);
        }
        for (int t = 0; t < T_; ++t)
            super(t, 0, true, false, cur_out + (size_t)t * 16384, (long)T_ * 16384, cbuf, 16384L);
        {
            int t4g = N_ * 256 * 128 / 4, t4u = N_ * 256 * 64 / 4;
            k_wpool<<<(t4g + 255) / 256, 256, 0, stream>>>(ne, gw1, Wg1, 256, 32, t4g);
            k_wpool<<<(t4u + 255) / 256, 256, 0, stream>>>(ne, uw1, Wu1, 256, 16, t4u);
        }
        for (int t = 0; t < T_; ++t)
            super(0, t, false, true, cbuf, 16384L, cur_out + (size_t)t * 16384, (long)T_ * 16384);
    }
    (void)in_sizes; (void)n_in; (void)out_size;
}

// Round 20
// 695.163 us; speedup vs baseline: 3.4509x; 1.0155x over previous
//
#include <hip/hip_runtime.h>
#include <math.h>

// AVWDCRNN round 20 (all-f32). r19=706us (k_pm unroll16 -77us; k_a2 unroll8
// slightly negative). This round: revert k_a2 to r18 body (52us, occ 39%);
// k_pm j-loop unroll 16 -> 32 (VGPR ~150, below r16's 256 spill cliff).

#define NF __restrict__
constexpr int N_ = 256, B_ = 8, T_ = 12, H_ = 64, E_ = 16;

__global__ void k_sentinel(float* NF out) { out[0] = 1.0e6f; }

// ---------------- adj = softmax(relu(ne ne^T), axis=1) ----------------
__global__ void k_adj(const float* NF ne, float* NF adj) {
    int n = blockIdx.x, m = threadIdx.x;
    __shared__ float en[E_];
    __shared__ float red[256];
    if (m < E_) en[m] = ne[n * E_ + m];
    __syncthreads();
    float s = 0.f;
#pragma unroll
    for (int d = 0; d < E_; d++) s += en[d] * ne[m * E_ + d];
    s = fmaxf(s, 0.f);
    red[m] = s; __syncthreads();
    for (int st = 128; st > 0; st >>= 1) { if (m < st) red[m] = fmaxf(red[m], red[m + st]); __syncthreads(); }
    float mx = red[0]; __syncthreads();
    float e = __expf(s - mx);
    red[m] = e; __syncthreads();
    for (int st = 128; st > 0; st >>= 1) { if (m < st) red[m] += red[m + st]; __syncthreads(); }
    adj[(size_t)n * N_ + m] = e / red[0];
}

// ------------- all four biases in one launch -------------
__global__ void k_bias4(const float* NF ne, const float* NF gb0, const float* NF ub0,
                        const float* NF gb1, const float* NF ub1,
                        float* NF Bg0, float* NF Bu0, float* NF Bg1, float* NF Bu1) {
    int n = blockIdx.x, tid = threadIdx.x;
    __shared__ float e[E_];
    if (tid < E_) e[tid] = ne[n * E_ + tid];
    __syncthreads();
    if (tid < 128) {
        float a0 = 0.f, a1 = 0.f;
#pragma unroll
        for (int d = 0; d < E_; d++) { a0 = fmaf(e[d], gb0[d * 128 + tid], a0); a1 = fmaf(e[d], gb1[d * 128 + tid], a1); }
        Bg0[(size_t)n * 128 + tid] = a0; Bg1[(size_t)n * 128 + tid] = a1;
    } else {
        int o = tid - 128;
        float a0 = 0.f, a1 = 0.f;
#pragma unroll
        for (int d = 0; d < E_; d++) { a0 = fmaf(e[d], ub0[d * 64 + o], a0); a1 = fmaf(e[d], ub1[d * 64 + o], a1); }
        Bu0[(size_t)n * 64 + o] = a0; Bu1[(size_t)n * 64 + o] = a1;
    }
}

// ------------- single-buffer W pool (fallback tier) -------------
__global__ void k_wpool(const float* NF ne, const float* NF wp, float* NF W,
                        int I2, int O4, int total4) {
    int idx4 = blockIdx.x * 256 + threadIdx.x;
    if (idx4 >= total4) return;
    int o4 = idx4 % O4; int rem = idx4 / O4; int j = rem % I2; int n = rem / I2;
    const float* nrow = ne + n * E_;
    float ax = 0.f, ay = 0.f, az = 0.f, aw = 0.f;
#pragma unroll
    for (int d = 0; d < E_; d++) {
        float e = nrow[d];
        const float4 w = *(const float4*)&wp[(((size_t)d * I2 + j) * O4 + o4) * 4];
        ax = fmaf(e, w.x, ax); ay = fmaf(e, w.y, ay); az = fmaf(e, w.z, az); aw = fmaf(e, w.w, aw);
    }
    float4 r; r.x = ax; r.y = ay; r.z = az; r.w = aw;
    *(float4*)&W[(size_t)idx4 * 4] = r;
}

// ------------- all 4 W pools: reuse-blocked (64 col4 x 16 nodes/block) -------------
__global__ __launch_bounds__(256) void k_wpool4(const float* NF ne,
                         const float* NF gw0, const float* NF uw0,
                         const float* NF gw1, const float* NF uw1,
                         float* NF Wg0, float* NF Wu0, float* NF Wg1, float* NF Wu1) {
    int cb = blockIdx.x % 291, nb = blockIdx.x / 291;
    const float* wp; float* W; int O4, c0;
    if (cb < 66)       { wp = gw0; W = Wg0; O4 = 4224; c0 = cb * 64; }
    else if (cb < 99)  { wp = uw0; W = Wu0; O4 = 2112; c0 = (cb - 66) * 64; }
    else if (cb < 227) { wp = gw1; W = Wg1; O4 = 8192; c0 = (cb - 99) * 64; }
    else               { wp = uw1; W = Wu1; O4 = 4096; c0 = (cb - 227) * 64; }
    __shared__ float4 PL[16][64];
    __shared__ float  eL[16][17];
    int tid = threadIdx.x;
#pragma unroll
    for (int q = 0; q < 4; q++) {
        int idx = q * 256 + tid; int d = idx >> 6, c = idx & 63;
        PL[d][c] = *(const float4*)&wp[((size_t)d * O4 + c0 + c) * 4];
    }
    int n0 = nb * 16;
    { int nn = tid >> 4, d = tid & 15; eL[nn][d] = ne[(n0 + nn) * E_ + d]; }
    __syncthreads();
    int c = tid & 63, ng = tid >> 6;
#pragma unroll
    for (int q = 0; q < 4; q++) {
        int nn = ng * 4 + q;
        float ax = 0.f, ay = 0.f, az = 0.f, aw = 0.f;
#pragma unroll
        for (int d = 0; d < E_; d++) {
            float e = eL[nn][d];
            float4 w = PL[d][c];
            ax = fmaf(e, w.x, ax); ay = fmaf(e, w.y, ay);
            az = fmaf(e, w.z, az); aw = fmaf(e, w.w, aw);
        }
        float4 r; r.x = ax; r.y = ay; r.z = az; r.w = aw;
        *(float4*)&W[((size_t)(n0 + nn) * O4 + c0 + c) * 4] = r;
    }
}

// ------------- E[tb,i,j] = exp(-L1(pa_i, pa_j)) ; tiled 64x64 -------------
__global__ __launch_bounds__(256) void k_sub_t(const float* NF pa, float* NF Ebuf) {
    int bx = blockIdx.x, tb = blockIdx.y;    // grid (16, 96)
    int it = bx & 3, jt = bx >> 2;
    int t = tb / B_, b = tb % B_;
    const float* p = pa + ((size_t)b * T_ + t) * N_ * H_;
    __shared__ float piT[64][64];
    __shared__ float pjT[64][64];
    int tid = threadIdx.x;
    int i0 = it * 64, j0 = jt * 64;
#pragma unroll
    for (int q = 0; q < 4; q++) {
        int idx = q * 256 + tid; int hq = idx & 15, i = idx >> 4;
        float4 v = *(const float4*)&p[(size_t)(i0 + i) * 64 + hq * 4];
        piT[hq * 4 + 0][i] = v.x; piT[hq * 4 + 1][i] = v.y; piT[hq * 4 + 2][i] = v.z; piT[hq * 4 + 3][i] = v.w;
        float4 w = *(const float4*)&p[(size_t)(j0 + i) * 64 + hq * 4];
        pjT[hq * 4 + 0][i] = w.x; pjT[hq * 4 + 1][i] = w.y; pjT[hq * 4 + 2][i] = w.z; pjT[hq * 4 + 3][i] = w.w;
    }
    __syncthreads();
    int jg = tid & 15, ig = tid >> 4;
    float acc[4][4];
#pragma unroll
    for (int a = 0; a < 4; a++)
#pragma unroll
        for (int c = 0; c < 4; c++) acc[a][c] = 0.f;
    for (int h = 0; h < 64; h++) {
        float4 a4 = *(const float4*)&piT[h][ig * 4];
        float4 b4 = *(const float4*)&pjT[h][jg * 4];
        float av[4] = { a4.x, a4.y, a4.z, a4.w };
        float bv[4] = { b4.x, b4.y, b4.z, b4.w };
#pragma unroll
        for (int a = 0; a < 4; a++)
#pragma unroll
            for (int c = 0; c < 4; c++) acc[a][c] += fabsf(av[a] - bv[c]);
    }
    float* dst = Ebuf + (size_t)tb * N_ * N_;
#pragma unroll
    for (int a = 0; a < 4; a++) {
        float4 o; o.x = __expf(-acc[a][0]); o.y = __expf(-acc[a][1]);
        o.z = __expf(-acc[a][2]); o.w = __expf(-acc[a][3]);
        *(float4*)&dst[(size_t)(i0 + ig * 4 + a) * N_ + j0 + jg * 4] = o;
    }
}

// ------------- column softmax normalize in-place -------------
__global__ void k_norm(float* NF Ebuf) {
    int tb = blockIdx.x, tid = threadIdx.x;   // 96 x 1024
    int j = tid & 255, q = tid >> 8;
    float* s = Ebuf + (size_t)tb * 65536;
    __shared__ float red[4][256];
    float S = 0.f;
    for (int i = q * 64; i < q * 64 + 64; ++i) S += s[(size_t)i * N_ + j];
    red[q][j] = S; __syncthreads();
    float inv = 1.f / (red[0][j] + red[1][j] + red[2][j] + red[3][j]);
    for (int i = q * 64; i < q * 64 + 64; ++i) s[(size_t)i * N_ + j] *= inv;
}

// ------------- A2[tb] = adj @ E'[tb]  (64x64 out-tiles, 32-m chunks; r18 body) -------------
__global__ __launch_bounds__(256) void k_a2(const float* NF adjm, const float* NF Ebuf, float* NF A2) {
    int rt = blockIdx.x & 3, ct = blockIdx.x >> 2;   // grid (16, 96)
    int tb = blockIdx.y;
    const float* U = Ebuf + (size_t)tb * N_ * N_;
    int r0 = rt * 64, c0 = ct * 64;
    __shared__ float SL[64][33];
    __shared__ float UL[32][72];
    int tid = threadIdx.x, cg = tid & 15, rg = tid >> 4;
    float acc[4][4];
#pragma unroll
    for (int a = 0; a < 4; a++)
#pragma unroll
        for (int c = 0; c < 4; c++) acc[a][c] = 0.f;
    for (int mc = 0; mc < 8; ++mc) {
        int m0 = mc * 32;
#pragma unroll
        for (int q = 0; q < 2; q++) {
            int idx = q * 256 + tid;
            int r = idx >> 3, mq = idx & 7;
            float4 v = *(const float4*)&adjm[(size_t)(r0 + r) * N_ + m0 + mq * 4];
            SL[r][mq * 4 + 0] = v.x; SL[r][mq * 4 + 1] = v.y;
            SL[r][mq * 4 + 2] = v.z; SL[r][mq * 4 + 3] = v.w;
            int mm = idx >> 4, c4 = idx & 15;
            float4 u = *(const float4*)&U[(size_t)(m0 + mm) * N_ + c0 + c4 * 4];
            *(float4*)&UL[mm][c4 * 4] = u;
        }
        __syncthreads();
        for (int mm = 0; mm < 32; ++mm) {
            float4 uv = *(const float4*)&UL[mm][cg * 4];
            float sv[4];
#pragma unroll
            for (int a = 0; a < 4; a++) sv[a] = SL[rg * 4 + a][mm];
#pragma unroll
            for (int a = 0; a < 4; a++) {
                acc[a][0] = fmaf(sv[a], uv.x, acc[a][0]);
                acc[a][1] = fmaf(sv[a], uv.y, acc[a][1]);
                acc[a][2] = fmaf(sv[a], uv.z, acc[a][2]);
                acc[a][3] = fmaf(sv[a], uv.w, acc[a][3]);
            }
        }
        __syncthreads();
    }
    float* dst = A2 + (size_t)tb * N_ * N_;
#pragma unroll
    for (int a = 0; a < 4; a++) {
        float4 o; o.x = acc[a][0]; o.y = acc[a][1]; o.z = acc[a][2]; o.w = acc[a][3];
        *(float4*)&dst[(size_t)(r0 + rg * 4 + a) * N_ + c0 + cg * 4] = o;
    }
}

// ------------- Y0X = S'_k @ x  (64-row tiles, 4-way m-split + shfl) -------------
__global__ __launch_bounds__(256) void k_y0x(const float* NF Ebuf, const float* NF A2,
                                             const float* NF x, float* NF y0x) {
    int rt = blockIdx.x, tbk = blockIdx.y;   // grid (4, 192)
    int tb = tbk >> 1, kk = tbk & 1;
    int t = tb / B_, b = tb % B_;
    const float* S = (kk ? A2 : Ebuf) + (size_t)tb * N_ * N_;
    const float* xb = x + ((size_t)b * T_ + t) * N_ * 2;
    __shared__ float SL[64][65];
    __shared__ float xw[64][2];
    int tid = threadIdx.x, rg = tid >> 2, mg = tid & 3;
    int r0 = rt * 64;
    float a0 = 0.f, a1 = 0.f;
    for (int mc = 0; mc < 4; ++mc) {
        int m0 = mc * 64;
#pragma unroll
        for (int q = 0; q < 4; q++) {
            int idx = q * 256 + tid; int r = idx >> 4, mq = idx & 15;
            float4 v = *(const float4*)&S[(size_t)(r0 + r) * N_ + m0 + mq * 4];
            SL[r][mq * 4 + 0] = v.x; SL[r][mq * 4 + 1] = v.y;
            SL[r][mq * 4 + 2] = v.z; SL[r][mq * 4 + 3] = v.w;
        }
        if (tid < 128) xw[tid >> 1][tid & 1] = xb[(size_t)(m0 + (tid >> 1)) * 2 + (tid & 1)];
        __syncthreads();
        for (int mm = mg * 16; mm < mg * 16 + 16; ++mm) {
            float s = SL[rg][mm];
            a0 = fmaf(s, xw[mm][0], a0); a1 = fmaf(s, xw[mm][1], a1);
        }
        __syncthreads();
    }
    a0 += __shfl_xor(a0, 1); a0 += __shfl_xor(a0, 2);
    a1 += __shfl_xor(a1, 1); a1 += __shfl_xor(a1, 2);
    if (mg == 0) {
        y0x[(((size_t)tb * 2 + kk) * N_ + r0 + rg) * 2 + 0] = a0;
        y0x[(((size_t)tb * 2 + kk) * N_ + r0 + rg) * 2 + 1] = a1;
    }
}

// ------------- sa init for both layers -------------
__global__ void k_init2(const float* NF ist, const float* NF pa,
                        float* NF u1sa0, float* NF u1sa1) {
    int idx = blockIdx.x * 256 + threadIdx.x;   // 262144
    int l = idx >> 17, r = idx & 131071;
    int b = r >> 14, rem = r & 16383;
    float v = ist[(size_t)l * 131072 + r] + pa[(size_t)b * T_ * 16384 + rem];
    if (l == 0) u1sa0[r] = v; else u1sa1[r] = v;
}

// ========== merged y phase, 2-way m-split (r15/r17 proven body) ==========
__global__ __launch_bounds__(256) void k_py(
    const float* NF Et0, const float* NF A2t0, const float* NF u0,
    const float* NF Et1, const float* NF A2t1, const float* NF cr, long crb,
    const float* NF u1s, float* NF yb0, float* NF yb1, int nb0, int cs_off)
{
    int bid = blockIdx.x, tid = threadIdx.x;
    int layer, rt, g, cs, ms;
    if (bid < 2 * nb0) { layer = 0; ms = bid & 1; int rest = bid >> 1; rt = rest & 3; g = rest >> 2; cs = 0; }
    else { int idx = bid - 2 * nb0; layer = 1; ms = idx & 1; int rest = idx >> 1; rt = rest & 3; g = (rest >> 2) & 15; cs = (rest >> 6) + cs_off; }
    int b = g >> 1, kk = g & 1;
    const float* S = (layer ? (kk ? A2t1 : Et1) : (kk ? A2t0 : Et0)) + (size_t)b * 65536;
    const float* U = layer ? (cs ? (u1s + (size_t)b * 16384) : (cr + (size_t)b * crb))
                           : (u0 + (size_t)b * 16384);
    __shared__ float SL[64][65];
    __shared__ float UL[64][72];
    int r0 = rt * 64;
    int cg = tid & 15, rg = tid >> 4;
    float acc[4][4];
#pragma unroll
    for (int a = 0; a < 4; a++)
#pragma unroll
        for (int c = 0; c < 4; c++) acc[a][c] = 0.f;
    for (int mc = 0; mc < 2; ++mc) {
        int m0 = ms * 128 + mc * 64;
#pragma unroll
        for (int q = 0; q < 4; q++) {
            int idx = q * 256 + tid; int r = idx >> 4, mq = idx & 15;
            float4 v = *(const float4*)&S[(size_t)(r0 + r) * N_ + m0 + mq * 4];
            SL[r][mq * 4 + 0] = v.x; SL[r][mq * 4 + 1] = v.y;
            SL[r][mq * 4 + 2] = v.z; SL[r][mq * 4 + 3] = v.w;
            float4 u = *(const float4*)&U[(size_t)(m0 + r) * 64 + mq * 4];
            *(float4*)&UL[r][mq * 4] = u;
        }
        __syncthreads();
        for (int mm = 0; mm < 64; ++mm) {
            float4 uv = *(const float4*)&UL[mm][cg * 4];
            float sv[4];
#pragma unroll
            for (int a = 0; a < 4; a++) sv[a] = SL[rg * 4 + a][mm];
#pragma unroll
            for (int a = 0; a < 4; a++) {
                acc[a][0] = fmaf(sv[a], uv.x, acc[a][0]);
                acc[a][1] = fmaf(sv[a], uv.y, acc[a][1]);
                acc[a][2] = fmaf(sv[a], uv.z, acc[a][2]);
                acc[a][3] = fmaf(sv[a], uv.w, acc[a][3]);
            }
        }
        __syncthreads();
    }
#pragma unroll
    for (int a = 0; a < 4; a++) {
        float4 o; o.x = acc[a][0]; o.y = acc[a][1]; o.z = acc[a][2]; o.w = acc[a][3];
        if (layer) *(float4*)&yb1[(size_t)ms * 524288 + ((size_t)g * 256 + r0 + rg * 4 + a) * 128 + cs * 64 + cg * 4] = o;
        else       *(float4*)&yb0[(size_t)ms * 262144 + ((size_t)g * 256 + r0 + rg * 4 + a) * 64 + cg * 4] = o;
    }
}

// ========== merged mm phase + GRU epilogues (j-loop unroll 32) ==========
template <int MODE>
__global__ __launch_bounds__(256) void k_pm(
    const float* NF yb0, const float* NF yb1, const float* NF Y0Xt,
    const float* NF Wl0, const float* NF Bl0, const float* NF Wl1, const float* NF Bl1,
    float* NF u1sa0, float* NF u2sa0, float* NF rb0,
    float* NF u1sa1, float* NF u2sa1, float* NF rb1,
    const float* NF pa, float* NF cw, long cwb, float* NF seq1,
    float* NF hid0, float* NF hid1, int t0, int t1, int nb0)
{
    constexpr int OT = (MODE == 0) ? 128 : 64;
    int bid = blockIdx.x, tid = threadIdx.x;
    int layer, n, os;
    if (bid < nb0) { layer = 0; n = bid & 255; os = bid >> 8; }
    else { int idx = bid - nb0; layer = 1; n = idx & 255; os = idx >> 8; }
    __shared__ float xg[256][12];
    if (layer == 0) {
        int b = tid >> 5, kk = (tid >> 4) & 1, c = (tid & 15) * 4;
        size_t base = (((size_t)(b * 2 + kk)) * 256 + n) * 64 + c;
        float4 v = *(const float4*)&yb0[base];
        float4 w = *(const float4*)&yb0[base + 262144];
        v.x += w.x; v.y += w.y; v.z += w.z; v.w += w.w;
        int j = kk * 66 + 2 + c;
        xg[j + 0][b] = v.x; xg[j + 1][b] = v.y; xg[j + 2][b] = v.z; xg[j + 3][b] = v.w;
        if (tid < 32) {
            int b2 = tid >> 2, k2 = (tid >> 1) & 1, c2 = tid & 1;
            xg[k2 * 66 + c2][b2] = Y0Xt[(((size_t)(b2 * 2 + k2)) * 256 + n) * 2 + c2];
        }
    } else {
        int b = tid >> 5, kk = (tid >> 4) & 1, cq = tid & 15;
#pragma unroll
        for (int q = 0; q < 2; q++) {
            int c = cq * 4 + q * 64;
            size_t base = (((size_t)(b * 2 + kk)) * 256 + n) * 128 + c;
            float4 v = *(const float4*)&yb1[base];
            float4 w = *(const float4*)&yb1[base + 524288];
            v.x += w.x; v.y += w.y; v.z += w.z; v.w += w.w;
            int j = kk * 128 + c;
            xg[j + 0][b] = v.x; xg[j + 1][b] = v.y; xg[j + 2][b] = v.z; xg[j + 3][b] = v.w;
        }
    }
    __syncthreads();
    int J2 = layer ? 256 : 132;
    const float* W = layer ? Wl1 : Wl0;
    const float* Bb = layer ? Bl1 : Bl0;
    int o_l = tid & 63, bg = tid >> 6;
    int o = os * 64 + o_l;
    float bias = Bb[(size_t)n * OT + o];
    float acc0 = bias, acc1 = bias;
    const float* Wn = W + (size_t)n * J2 * OT + o;
#pragma unroll 32
    for (int j = 0; j < J2; ++j) {
        float w = Wn[(size_t)j * OT];
        float2 xv = *(const float2*)&xg[j][bg * 2];
        acc0 = fmaf(xv.x, w, acc0); acc1 = fmaf(xv.y, w, acc1);
    }
#pragma unroll
    for (int q = 0; q < 2; ++q) {
        int b = bg * 2 + q;
        float a = q ? acc1 : acc0;
        size_t bn = (size_t)b * 256 + n;
        if (MODE == 0) {
            float v = 1.f / (1.f + __expf(-a));
            if (layer == 0) {
                if (o < 64) u2sa0[bn * 64 + o] = v * u1sa0[bn * 64 + o];
                else        rb0[bn * 64 + (o - 64)] = v;
            } else {
                if (o < 64) u2sa1[bn * 64 + o] = v * u1sa1[bn * 64 + o];
                else        rb1[bn * 64 + (o - 64)] = v;
            }
        } else {
            float hc = tanhf(a);
            if (layer == 0) {
                float r = rb0[bn * 64 + o];
                float s = u1sa0[bn * 64 + o];
                float ns = hc + r * (s - hc);
                cw[(size_t)b * cwb + (size_t)n * 64 + o] = ns;
                if (t0 < T_ - 1) u1sa0[bn * 64 + o] = ns + pa[(((size_t)b * T_ + t0 + 1) * 256 + n) * 64 + o];
                else             hid0[bn * 64 + o] = ns;
            } else {
                float r = rb1[bn * 64 + o];
                float s = u1sa1[bn * 64 + o];
                float ns = hc + r * (s - hc);
                seq1[(((size_t)b * T_ + t1) * 256 + n) * 64 + o] = ns;
                if (t1 < T_ - 1) u1sa1[bn * 64 + o] = ns + pa[(((size_t)b * T_ + t1 + 1) * 256 + n) * 64 + o];
                else             hid1[bn * 64 + o] = ns;
            }
        }
    }
}

extern "C" void kernel_launch(void* const* d_in, const int* in_sizes, int n_in,
                              void* d_out, int out_size, void* d_ws, size_t ws_size,
                              hipStream_t stream) {
    const float* x   = (const float*)d_in[0];
    const float* ist = (const float*)d_in[1];
    const float* ne  = (const float*)d_in[2];
    const float* pa  = (const float*)d_in[3];
    const float* gw0 = (const float*)d_in[4];
    const float* gb0 = (const float*)d_in[5];
    const float* uw0 = (const float*)d_in[6];
    const float* ub0 = (const float*)d_in[7];
    const float* gw1 = (const float*)d_in[8];
    const float* gb1 = (const float*)d_in[9];
    const float* uw1 = (const float*)d_in[10];
    const float* ub1 = (const float*)d_in[11];
    float* out = (float*)d_out;
    char*  base = (char*)d_ws;

    float* cur_out = out;                                   // (B,T,N,H)
    float* hid_out = out + (size_t)B_ * T_ * N_ * H_;       // (2,B,N,H)
    float* hid0 = hid_out, * hid1 = hid_out + 131072;

    size_t off = 0;
    auto carve = [&](size_t bytes) { char* p = base + off; off += (bytes + 255) & ~(size_t)255; return p; };
    float* adjw  = (float*)carve(65536ull * 4);
    float* Ebuf  = (float*)carve(6291456ull * 4);
    float* A2    = (float*)carve(6291456ull * 4);
    float* Bg0   = (float*)carve(32768ull * 4);
    float* Bu0   = (float*)carve(16384ull * 4);
    float* Bg1   = (float*)carve(32768ull * 4);
    float* Bu1   = (float*)carve(16384ull * 4);
    float* u1sa0 = (float*)carve(131072ull * 4);
    float* u2sa0 = (float*)carve(131072ull * 4);
    float* rb0   = (float*)carve(131072ull * 4);
    float* u1sa1 = (float*)carve(131072ull * 4);
    float* u2sa1 = (float*)carve(131072ull * 4);
    float* rb1   = (float*)carve(131072ull * 4);
    float* cbuf  = (float*)carve(131072ull * 4);
    float* yb0   = (float*)carve(524288ull * 4);    // 2 m-split slots
    float* yb1   = (float*)carve(1048576ull * 4);   // 2 m-split slots
    float* y0x   = hid1;   // alias: y0x lives in hid1 region until final phase
    size_t common_end = off;
    float* Wg0 = (float*)carve(4325376ull * 4);
    float* Wu0 = (float*)carve(2162688ull * 4);
    float* Wg1 = (float*)carve(8388608ull * 4);
    float* Wu1 = (float*)carve(4194304ull * 4);
    bool pipe = (off <= ws_size);
    if (!pipe) {
        off = common_end;
        float* WgS = (float*)carve(8388608ull * 4);
        float* WuS = (float*)carve(4194304ull * 4);
        if (off > ws_size) { k_sentinel<<<1, 1, 0, stream>>>(out); return; }
        Wg0 = Wg1 = WgS; Wu0 = Wu1 = WuS;
    }

    // ---- time-invariant precompute ----
    k_adj<<<256, 256, 0, stream>>>(ne, adjw);
    k_sub_t<<<dim3(16, 96), 256, 0, stream>>>(pa, Ebuf);
    k_norm<<<96, 1024, 0, stream>>>(Ebuf);
    k_a2<<<dim3(16, 96), 256, 0, stream>>>(adjw, Ebuf, A2);
    k_y0x<<<dim3(4, 192), 256, 0, stream>>>(Ebuf, A2, x, y0x);
    k_bias4<<<256, 192, 0, stream>>>(ne, gb0, ub0, gb1, ub1, Bg0, Bu0, Bg1, Bu1);
    k_init2<<<1024, 256, 0, stream>>>(ist, pa, u1sa0, u1sa1);

    // one super-step: l0 at t0 (if a0), l1 at t1 (if a1)
    auto super = [&](int t0, int t1, bool a0, bool a1, float* cw, long cwb,
                     const float* cr, long crb) {
        const float* Et0  = Ebuf + (size_t)t0 * B_ * 65536;
        const float* A2t0 = A2   + (size_t)t0 * B_ * 65536;
        const float* Et1  = Ebuf + (size_t)t1 * B_ * 65536;
        const float* A2t1 = A2   + (size_t)t1 * B_ * 65536;
        const float* YXt  = y0x  + (size_t)t0 * B_ * 2 * N_ * 2;
        int y0n = a0 ? 64 : 0;
        int m0g = a0 ? 512 : 0, m0u = a0 ? 256 : 0;
        k_py<<<2 * y0n + (a1 ? 256 : 0), 256, 0, stream>>>(Et0, A2t0, u1sa0, Et1, A2t1, cr, crb, u1sa1, yb0, yb1, y0n, 0);
        k_pm<0><<<m0g + (a1 ? 512 : 0), 256, 0, stream>>>(yb0, yb1, YXt, Wg0, Bg0, Wg1, Bg1,
            u1sa0, u2sa0, rb0, u1sa1, u2sa1, rb1, pa, cw, cwb, cur_out, hid0, hid1, t0, t1, m0g);
        k_py<<<2 * y0n + (a1 ? 128 : 0), 256, 0, stream>>>(Et0, A2t0, u2sa0, Et1, A2t1, cr, crb, u2sa1, yb0, yb1, y0n, 1);
        k_pm<1><<<m0u + (a1 ? 256 : 0), 256, 0, stream>>>(yb0, yb1, YXt, Wu0, Bu0, Wu1, Bu1,
            u1sa0, u2sa0, rb0, u1sa1, u2sa1, rb1, pa, cw, cwb, cur_out, hid0, hid1, t0, t1, m0u);
    };

    if (pipe) {
        k_wpool4<<<4656, 256, 0, stream>>>(ne, gw0, uw0, gw1, uw1, Wg0, Wu0, Wg1, Wu1);
        for (int s = 0; s <= 12; ++s) {
            bool a0 = (s < 12), a1 = (s >= 1);
            int t0 = a0 ? s : 11, t1 = a1 ? s - 1 : 0;
            super(t0, t1, a0, a1, cbuf, 16384L, cbuf, 16384L);
        }
    } else {
        {
            int t4g = N_ * 132 * 128 / 4, t4u = N_ * 132 * 64 / 4;
            k_wpool<<<(t4g + 255) / 256, 256, 0, stream>>>(ne, gw0, Wg0, 132, 32, t4g);
            k_wpool<<<(t4u + 255) / 256, 256, 0, stream>>>(ne, uw0, Wu0, 132, 16, t4u);
        }
        for (int t = 0; t < T_; ++t)
            super(t, 0, true, false, cur_out + (size_t)t * 16384, (long)T_ * 16384, cbuf, 16384L);
        {
            int t4g = N_ * 256 * 128 / 4, t4u = N_ * 256 * 64 / 4;
            k_wpool<<<(t4g + 255) / 256, 256, 0, stream>>>(ne, gw1, Wg1, 256, 32, t4g);
            k_wpool<<<(t4u + 255) / 256, 256, 0, stream>>>(ne, uw1, Wu1, 256, 16, t4u);
        }
        for (int t = 0; t < T_; ++t)
            super(0, t, false, true, cbuf, 16384L, cur_out + (size_t)t * 16384, (long)T_ * 16384);
    }
    (void)in_sizes; (void)n_in; (void)out_size;
}